// Round 3
// baseline (1520.651 us; speedup 1.0000x reference)
//
#include <hip/hip_runtime.h>
#include <hip/hip_bf16.h>

#define NN 50000
#define NE 800000

// monotone float <-> uint mapping for atomicMax on floats
__device__ __forceinline__ unsigned fmap(float x) {
    unsigned u = __float_as_uint(x);
    return (u & 0x80000000u) ? ~u : (u | 0x80000000u);
}
__device__ __forceinline__ float funmap(unsigned u) {
    return (u & 0x80000000u) ? __uint_as_float(u & 0x7FFFFFFFu) : __uint_as_float(~u);
}

// feat[n,m] = sum_k X[n,k] * W[k,m]   (naive thread-per-output)
__global__ void gemm_naive(const float* __restrict__ X, const float* __restrict__ W,
                           float* __restrict__ out, int N, int K, int M) {
    int idx = blockIdx.x * blockDim.x + threadIdx.x;
    if (idx >= N * M) return;
    int n = idx / M, m = idx - n * M;
    const float* xr = X + (size_t)n * K;
    float acc = 0.f;
    for (int k = 0; k < K; ++k)
        acc += xr[k] * W[k * M + m];
    out[idx] = acc;
}

// el[n] = feat[n,:].al ; er[n] = feat[n,:].ar   (one wave per node)
__global__ void attn_scores(const float* __restrict__ feat, const float* __restrict__ al,
                            const float* __restrict__ ar, float* __restrict__ el,
                            float* __restrict__ er, int N, int F) {
    int wave = (blockIdx.x * blockDim.x + threadIdx.x) >> 6;
    int lane = threadIdx.x & 63;
    if (wave >= N) return;
    float a = 0.f, b = 0.f;
    for (int f = lane; f < F; f += 64) {
        float v = feat[(size_t)wave * F + f];
        a += v * al[f];
        b += v * ar[f];
    }
    for (int o = 32; o; o >>= 1) { a += __shfl_down(a, o); b += __shfl_down(b, o); }
    if (lane == 0) { el[wave] = a; er[wave] = b; }
}

__global__ void edge_logit_max(const int* __restrict__ src, const int* __restrict__ dst,
                               const float* __restrict__ el, const float* __restrict__ er,
                               float* __restrict__ ebuf, unsigned* __restrict__ emaxu, int E) {
    int e = blockIdx.x * blockDim.x + threadIdx.x;
    if (e >= E) return;
    float v = el[src[e]] + er[dst[e]];
    v = (v >= 0.f) ? v : 0.2f * v;  // leaky_relu 0.2
    ebuf[e] = v;
    atomicMax(&emaxu[dst[e]], fmap(v));
}

__global__ void edge_exp_sum(const int* __restrict__ dst, const float* __restrict__ ebuf,
                             const unsigned* __restrict__ emaxu, float* __restrict__ exbuf,
                             float* __restrict__ denom, int E) {
    int e = blockIdx.x * blockDim.x + threadIdx.x;
    if (e >= E) return;
    int d = dst[e];
    float ex = __expf(ebuf[e] - funmap(emaxu[d]));
    exbuf[e] = ex;
    atomicAdd(&denom[d], ex);
}

// one wave per edge: hout[dst,:] += feat[src,:] * alpha
__global__ void edge_scatter(const int* __restrict__ src, const int* __restrict__ dst,
                             const float* __restrict__ exbuf, const float* __restrict__ denom,
                             const float* __restrict__ feat, float* __restrict__ hout,
                             int E, int F) {
    int wave = (blockIdx.x * blockDim.x + threadIdx.x) >> 6;
    int lane = threadIdx.x & 63;
    if (wave >= E) return;
    int s = src[wave], d = dst[wave];
    float alpha = exbuf[wave] / denom[d];
    for (int f = lane; f < F; f += 64)
        atomicAdd(&hout[(size_t)d * F + f], feat[(size_t)s * F + f] * alpha);
}

__global__ void bias_act(float* __restrict__ h, const float* __restrict__ bias,
                         int total, int F, int do_relu) {
    int i = blockIdx.x * blockDim.x + threadIdx.x;
    if (i >= total) return;
    float v = h[i] + bias[i % F];
    if (do_relu) v = fmaxf(v, 0.f);
    h[i] = v;
}

// write f32 h to d_out, and per-node link-pred partial scores (F=64 fixed)
__global__ void finalize_h(const float* __restrict__ h, float* __restrict__ outh,
                           const float* __restrict__ lpW, float* __restrict__ s1,
                           float* __restrict__ s2, int N) {
    int wave = (blockIdx.x * blockDim.x + threadIdx.x) >> 6;
    int lane = threadIdx.x & 63;
    if (wave >= N) return;
    float v = h[(size_t)wave * 64 + lane];
    outh[(size_t)wave * 64 + lane] = v;
    float a = v * lpW[lane];
    float b = v * lpW[64 + lane];
    for (int o = 32; o; o >>= 1) { a += __shfl_down(a, o); b += __shfl_down(b, o); }
    if (lane == 0) { s1[wave] = a; s2[wave] = b; }
}

__global__ void scores_k(const int* __restrict__ s, const int* __restrict__ d,
                         const float* __restrict__ s1, const float* __restrict__ s2,
                         const float* __restrict__ lpb, float* __restrict__ out, int E) {
    int i = blockIdx.x * blockDim.x + threadIdx.x;
    if (i >= E) return;
    out[i] = s1[s[i]] + s2[d[i]] + lpb[0];
}

struct Scratch {
    float* feat; float* hA; float* hB;
    float* el; float* er; unsigned* emaxu; float* denom;
    float* ebuf; float* exbuf; float* s1; float* s2;
};

static void run_layer(const float* hin, const float* W, const float* al,
                      const float* ar, const float* b, int K, int M, bool relu,
                      const int* src, const int* dst, float* hout, const Scratch& S,
                      hipStream_t stream) {
    const int N = NN, E = NE;
    hipMemsetAsync(hout, 0, (size_t)N * M * 4, stream);
    hipMemsetAsync(S.emaxu, 0, (size_t)N * 4, stream);
    hipMemsetAsync(S.denom, 0, (size_t)N * 4, stream);

    int total = N * M;
    int gg = (total + 255) / 256;
    gemm_naive<<<gg, 256, 0, stream>>>(hin, W, S.feat, N, K, M);
    attn_scores<<<(N + 3) / 4, 256, 0, stream>>>(S.feat, al, ar, S.el, S.er, N, M);
    edge_logit_max<<<(E + 255) / 256, 256, 0, stream>>>(src, dst, S.el, S.er, S.ebuf, S.emaxu, E);
    edge_exp_sum<<<(E + 255) / 256, 256, 0, stream>>>(dst, S.ebuf, S.emaxu, S.exbuf, S.denom, E);
    edge_scatter<<<(E + 3) / 4, 256, 0, stream>>>(src, dst, S.exbuf, S.denom, S.feat, hout, E, M);
    bias_act<<<(total + 255) / 256, 256, 0, stream>>>(hout, b, total, M, relu ? 1 : 0);
}

extern "C" void kernel_launch(void* const* d_in, const int* in_sizes, int n_in,
                              void* d_out, int out_size, void* d_ws, size_t ws_size,
                              hipStream_t stream) {
    const float* x   = (const float*)d_in[0];
    const float* W1  = (const float*)d_in[1];
    const float* al1 = (const float*)d_in[2];
    const float* ar1 = (const float*)d_in[3];
    const float* b1  = (const float*)d_in[4];
    const float* W2  = (const float*)d_in[5];
    const float* al2 = (const float*)d_in[6];
    const float* ar2 = (const float*)d_in[7];
    const float* b2  = (const float*)d_in[8];
    const float* W3  = (const float*)d_in[9];
    const float* al3 = (const float*)d_in[10];
    const float* ar3 = (const float*)d_in[11];
    const float* b3  = (const float*)d_in[12];
    const float* lpW = (const float*)d_in[13];
    const float* lpb = (const float*)d_in[14];
    const int* src  = (const int*)d_in[15];
    const int* dst  = (const int*)d_in[16];
    const int* nsrc = (const int*)d_in[17];
    const int* ndst = (const int*)d_in[18];

    float* w = (float*)d_ws;
    Scratch S;
    S.feat  = w;                 w += (size_t)NN * 128;
    S.hA    = w;                 w += (size_t)NN * 128;
    S.hB    = w;                 w += (size_t)NN * 128;
    S.el    = w;                 w += NN;
    S.er    = w;                 w += NN;
    S.emaxu = (unsigned*)w;      w += NN;
    S.denom = w;                 w += NN;
    S.ebuf  = w;                 w += NE;
    S.exbuf = w;                 w += NE;
    S.s1    = w;                 w += NN;
    S.s2    = w;                 w += NN;

    // layer 1: x[50000,128] @ W1[128,64] -> hA, relu
    run_layer(x, W1, al1, ar1, b1, 128, 64, true, src, dst, S.hA, S, stream);
    // layer 2: hA[50000,64] @ W2[64,128] -> hB, relu
    run_layer(S.hA, W2, al2, ar2, b2, 64, 128, true, src, dst, S.hB, S, stream);
    // layer 3: hB[50000,128] @ W3[128,64] -> hA (reuse), no relu
    run_layer(S.hB, W3, al3, ar3, b3, 128, 64, false, src, dst, S.hA, S, stream);

    float* out_h   = (float*)d_out;
    float* out_pos = out_h + (size_t)NN * 64;
    float* out_neg = out_pos + NE;

    finalize_h<<<(NN + 3) / 4, 256, 0, stream>>>(S.hA, out_h, lpW, S.s1, S.s2, NN);
    scores_k<<<(NE + 255) / 256, 256, 0, stream>>>(src, dst, S.s1, S.s2, lpb, out_pos, NE);
    scores_k<<<(NE + 255) / 256, 256, 0, stream>>>(nsrc, ndst, S.s1, S.s2, lpb, out_neg, NE);
}

// Round 4
// 561.529 us; speedup vs baseline: 2.7081x; 2.7081x over previous
//
#include <hip/hip_runtime.h>
#include <hip/hip_bf16.h>

#define NN 50000
#define NE 800000

__device__ __forceinline__ float leaky(float v) { return (v >= 0.f) ? v : 0.2f * v; }

// ---------------- CSR build (graph is identical for all 3 layers) ----------------

__global__ void hist_k(const int* __restrict__ dst, int* __restrict__ cnt, int E) {
    int e = blockIdx.x * blockDim.x + threadIdx.x;
    if (e < E) atomicAdd(&cnt[dst[e]], 1);
}

// exclusive scan of cnt[0..n) -> off (and cursor copy); off[n] = total. One block, 1024 thr.
__global__ void scan_off(const int* __restrict__ cnt, int* __restrict__ off,
                         int* __restrict__ cursor, int n) {
    __shared__ int ws[17];
    __shared__ int carry_s;
    int t = threadIdx.x;
    int lane = t & 63, w = t >> 6;
    if (t == 0) carry_s = 0;
    __syncthreads();
    for (int base = 0; base < n; base += 1024) {
        int v = (base + t < n) ? cnt[base + t] : 0;
        int sc = v;  // inclusive scan within wave
        for (int o = 1; o < 64; o <<= 1) {
            int x = __shfl_up(sc, o);
            if (lane >= o) sc += x;
        }
        if (lane == 63) ws[w] = sc;
        __syncthreads();
        if (t == 0) {
            int run = 0;
            for (int i = 0; i < 16; ++i) { int tmp = ws[i]; ws[i] = run; run += tmp; }
            ws[16] = run;  // block total
        }
        __syncthreads();
        int carry = carry_s;
        int exc = carry + ws[w] + sc - v;  // exclusive global prefix
        if (base + t < n) { off[base + t] = exc; cursor[base + t] = exc; }
        __syncthreads();
        if (t == 0) carry_s = carry + ws[16];
        __syncthreads();
    }
    if (t == 0) off[n] = carry_s;
}

__global__ void csr_fill(const int* __restrict__ src, const int* __restrict__ dst,
                         int* __restrict__ cursor, int* __restrict__ csrsrc, int E) {
    int e = blockIdx.x * blockDim.x + threadIdx.x;
    if (e >= E) return;
    int pos = atomicAdd(&cursor[dst[e]], 1);
    csrsrc[pos] = src[e];
}

// ---------------- per-layer kernels ----------------

// feat[n, tm..tm+3] — 4 outputs per thread, float4 W loads
__global__ void gemm_t4(const float* __restrict__ X, const float* __restrict__ W,
                        float* __restrict__ out, int N, int K, int M, int ltpr) {
    int idx = blockIdx.x * blockDim.x + threadIdx.x;
    int n = idx >> ltpr;
    int tm = (idx & ((1 << ltpr) - 1)) << 2;
    if (n >= N) return;
    const float* xr = X + (size_t)n * K;
    float ax = 0.f, ay = 0.f, az = 0.f, aw = 0.f;
    #pragma unroll 8
    for (int k = 0; k < K; ++k) {
        float xv = xr[k];
        float4 wv = *reinterpret_cast<const float4*>(&W[k * M + tm]);
        ax += xv * wv.x; ay += xv * wv.y; az += xv * wv.z; aw += xv * wv.w;
    }
    float4 r; r.x = ax; r.y = ay; r.z = az; r.w = aw;
    *reinterpret_cast<float4*>(&out[(size_t)n * M + tm]) = r;
}

// el[n] = feat[n,:].al ; er[n] = feat[n,:].ar   (one wave per node)
__global__ void attn_scores(const float* __restrict__ feat, const float* __restrict__ al,
                            const float* __restrict__ ar, float* __restrict__ el,
                            float* __restrict__ er, int N, int F) {
    int wave = (blockIdx.x * blockDim.x + threadIdx.x) >> 6;
    int lane = threadIdx.x & 63;
    if (wave >= N) return;
    float a = 0.f, b = 0.f;
    for (int f = lane; f < F; f += 64) {
        float v = feat[(size_t)wave * F + f];
        a += v * al[f];
        b += v * ar[f];
    }
    for (int o = 32; o; o >>= 1) { a += __shfl_down(a, o); b += __shfl_down(b, o); }
    if (lane == 0) { el[wave] = a; er[wave] = b; }
}

// one wave per node: edge-softmax + weighted gather + bias + act, no atomics
__global__ void gat_agg(const int* __restrict__ off, const int* __restrict__ csrsrc,
                        const float* __restrict__ el, const float* __restrict__ er,
                        const float* __restrict__ feat, const float* __restrict__ bias,
                        float* __restrict__ hout, int N, int F, int do_relu) {
    int node = (blockIdx.x * blockDim.x + threadIdx.x) >> 6;
    int lane = threadIdx.x & 63;
    if (node >= N) return;
    int start = off[node], deg = off[node + 1] - start;
    float ern = er[node];

    // lane-parallel logits; lane i holds edge (start+i) for i<64
    int s0 = 0; float e0 = -1e30f;
    if (lane < deg) { s0 = csrsrc[start + lane]; e0 = leaky(el[s0] + ern); }
    float m = e0;
    for (int i = 64 + lane; i < deg; i += 64) {  // rare tail (deg>64)
        int s = csrsrc[start + i];
        m = fmaxf(m, leaky(el[s] + ern));
    }
    for (int o = 32; o; o >>= 1) m = fmaxf(m, __shfl_xor(m, o));

    float p0 = (lane < deg) ? __expf(e0 - m) : 0.f;
    float ssum = p0;
    for (int i = 64 + lane; i < deg; i += 64) {
        int s = csrsrc[start + i];
        ssum += __expf(leaky(el[s] + ern) - m);
    }
    for (int o = 32; o; o >>= 1) ssum += __shfl_xor(ssum, o);
    float inv = (deg > 0) ? 1.f / ssum : 0.f;

    // gather-accumulate
    float acc0 = 0.f, acc1 = 0.f;
    int head = (deg < 64) ? deg : 64;
    for (int i = 0; i < head; ++i) {
        float p = __shfl(p0, i);
        int sN = __shfl(s0, i);
        acc0 += p * feat[(size_t)sN * F + lane];
        if (F == 128) acc1 += p * feat[(size_t)sN * F + 64 + lane];
    }
    for (int i = 64; i < deg; ++i) {  // rare tail: recompute p (broadcast loads)
        int sN = csrsrc[start + i];
        float p = __expf(leaky(el[sN] + ern) - m);
        acc0 += p * feat[(size_t)sN * F + lane];
        if (F == 128) acc1 += p * feat[(size_t)sN * F + 64 + lane];
    }

    float v0 = acc0 * inv + bias[lane];
    if (do_relu) v0 = fmaxf(v0, 0.f);
    hout[(size_t)node * F + lane] = v0;
    if (F == 128) {
        float v1 = acc1 * inv + bias[64 + lane];
        if (do_relu) v1 = fmaxf(v1, 0.f);
        hout[(size_t)node * F + 64 + lane] = v1;
    }
}

// write f32 h to d_out, and per-node link-pred partial scores (F=64 fixed)
__global__ void finalize_h(const float* __restrict__ h, float* __restrict__ outh,
                           const float* __restrict__ lpW, float* __restrict__ s1,
                           float* __restrict__ s2, int N) {
    int wave = (blockIdx.x * blockDim.x + threadIdx.x) >> 6;
    int lane = threadIdx.x & 63;
    if (wave >= N) return;
    float v = h[(size_t)wave * 64 + lane];
    outh[(size_t)wave * 64 + lane] = v;
    float a = v * lpW[lane];
    float b = v * lpW[64 + lane];
    for (int o = 32; o; o >>= 1) { a += __shfl_down(a, o); b += __shfl_down(b, o); }
    if (lane == 0) { s1[wave] = a; s2[wave] = b; }
}

__global__ void scores_k(const int* __restrict__ s, const int* __restrict__ d,
                         const float* __restrict__ s1, const float* __restrict__ s2,
                         const float* __restrict__ lpb, float* __restrict__ out, int E) {
    int i = blockIdx.x * blockDim.x + threadIdx.x;
    if (i >= E) return;
    out[i] = s1[s[i]] + s2[d[i]] + lpb[0];
}

// ---------------- driver ----------------

struct Scratch {
    float* feat; float* hA; float* hB;
    float* el; float* er; float* s1; float* s2;
    int* cnt; int* off; int* cursor; int* csrsrc;
};

static void run_layer(const float* hin, const float* W, const float* al,
                      const float* ar, const float* b, int K, int M, bool relu,
                      float* hout, const Scratch& S, hipStream_t stream) {
    const int N = NN;
    int ltpr = (M == 64) ? 4 : 5;  // threads-per-row = M/4
    int tthreads = N * (M >> 2);
    gemm_t4<<<(tthreads + 255) / 256, 256, 0, stream>>>(hin, W, S.feat, N, K, M, ltpr);
    attn_scores<<<(N + 3) / 4, 256, 0, stream>>>(S.feat, al, ar, S.el, S.er, N, M);
    gat_agg<<<(N + 3) / 4, 256, 0, stream>>>(S.off, S.csrsrc, S.el, S.er, S.feat, b,
                                             hout, N, M, relu ? 1 : 0);
}

extern "C" void kernel_launch(void* const* d_in, const int* in_sizes, int n_in,
                              void* d_out, int out_size, void* d_ws, size_t ws_size,
                              hipStream_t stream) {
    const float* x   = (const float*)d_in[0];
    const float* W1  = (const float*)d_in[1];
    const float* al1 = (const float*)d_in[2];
    const float* ar1 = (const float*)d_in[3];
    const float* b1  = (const float*)d_in[4];
    const float* W2  = (const float*)d_in[5];
    const float* al2 = (const float*)d_in[6];
    const float* ar2 = (const float*)d_in[7];
    const float* b2  = (const float*)d_in[8];
    const float* W3  = (const float*)d_in[9];
    const float* al3 = (const float*)d_in[10];
    const float* ar3 = (const float*)d_in[11];
    const float* b3  = (const float*)d_in[12];
    const float* lpW = (const float*)d_in[13];
    const float* lpb = (const float*)d_in[14];
    const int* src  = (const int*)d_in[15];
    const int* dst  = (const int*)d_in[16];
    const int* nsrc = (const int*)d_in[17];
    const int* ndst = (const int*)d_in[18];

    char* w = (char*)d_ws;
    Scratch S;
    S.feat   = (float*)w; w += (size_t)NN * 128 * 4;
    S.hA     = (float*)w; w += (size_t)NN * 64 * 4;
    S.hB     = (float*)w; w += (size_t)NN * 128 * 4;
    S.el     = (float*)w; w += (size_t)NN * 4;
    S.er     = (float*)w; w += (size_t)NN * 4;
    S.s1     = (float*)w; w += (size_t)NN * 4;
    S.s2     = (float*)w; w += (size_t)NN * 4;
    S.cnt    = (int*)w;   w += (size_t)NN * 4;
    S.off    = (int*)w;   w += (size_t)(NN + 1) * 4;
    S.cursor = (int*)w;   w += (size_t)NN * 4;
    S.csrsrc = (int*)w;   w += (size_t)NE * 4;

    // build dst-CSR once; reused by all 3 layers
    hipMemsetAsync(S.cnt, 0, (size_t)NN * 4, stream);
    hist_k<<<(NE + 255) / 256, 256, 0, stream>>>(dst, S.cnt, NE);
    scan_off<<<1, 1024, 0, stream>>>(S.cnt, S.off, S.cursor, NN);
    csr_fill<<<(NE + 255) / 256, 256, 0, stream>>>(src, dst, S.cursor, S.csrsrc, NE);

    // layer 1: x[50000,128] @ W1[128,64] -> hA, relu
    run_layer(x, W1, al1, ar1, b1, 128, 64, true, S.hA, S, stream);
    // layer 2: hA[50000,64] @ W2[64,128] -> hB, relu
    run_layer(S.hA, W2, al2, ar2, b2, 64, 128, true, S.hB, S, stream);
    // layer 3: hB[50000,128] @ W3[128,64] -> hA (reuse), no relu
    run_layer(S.hB, W3, al3, ar3, b3, 128, 64, false, S.hA, S, stream);

    float* out_h   = (float*)d_out;
    float* out_pos = out_h + (size_t)NN * 64;
    float* out_neg = out_pos + NE;

    finalize_h<<<(NN + 3) / 4, 256, 0, stream>>>(S.hA, out_h, lpW, S.s1, S.s2, NN);
    scores_k<<<(NE + 255) / 256, 256, 0, stream>>>(src, dst, S.s1, S.s2, lpb, out_pos, NE);
    scores_k<<<(NE + 255) / 256, 256, 0, stream>>>(nsrc, ndst, S.s1, S.s2, lpb, out_neg, NE);
}

// Round 5
// 347.971 us; speedup vs baseline: 4.3700x; 1.6137x over previous
//
#include <hip/hip_runtime.h>
#include <hip/hip_bf16.h>

#define NN 50000
#define NE 800000

__device__ __forceinline__ float leaky(float v) { return (v >= 0.f) ? v : 0.2f * v; }

// ---------------- CSR build (graph is identical for all 3 layers) ----------------

__global__ void hist_k(const int* __restrict__ dst, int* __restrict__ cnt, int E) {
    int e = blockIdx.x * blockDim.x + threadIdx.x;
    if (e < E) atomicAdd(&cnt[dst[e]], 1);
}

// per-block exclusive scan (1024 threads/block); writes exclusive-within-block to off, block sum out
__global__ void scan_blocks(const int* __restrict__ cnt, int* __restrict__ off,
                            int* __restrict__ blocksum, int n) {
    __shared__ int ws[16];
    int t = threadIdx.x;
    int idx = blockIdx.x * 1024 + t;
    int lane = t & 63, w = t >> 6;
    int v = (idx < n) ? cnt[idx] : 0;
    int sc = v;
    for (int o = 1; o < 64; o <<= 1) {
        int x = __shfl_up(sc, o);
        if (lane >= o) sc += x;
    }
    if (lane == 63) ws[w] = sc;
    __syncthreads();
    if (t == 0) {
        int run = 0;
        #pragma unroll
        for (int i = 0; i < 16; ++i) { int tmp = ws[i]; ws[i] = run; run += tmp; }
        blocksum[blockIdx.x] = run;
    }
    __syncthreads();
    if (idx < n) off[idx] = ws[w] + sc - v;
}

// scan the (<=64) block sums in one wave; write total to off_end
__global__ void scan_sums(int* __restrict__ blocksum, int nb, int* __restrict__ off_end) {
    int t = threadIdx.x;  // 64 threads
    int v = (t < nb) ? blocksum[t] : 0;
    int sc = v;
    for (int o = 1; o < 64; o <<= 1) {
        int x = __shfl_up(sc, o);
        if (t >= o) sc += x;
    }
    if (t < nb) blocksum[t] = sc - v;
    if (t == 63) *off_end = sc;
}

__global__ void scan_apply(int* __restrict__ off, const int* __restrict__ blocksum,
                           int* __restrict__ cursor, int n) {
    int i = blockIdx.x * blockDim.x + threadIdx.x;
    if (i >= n) return;
    int v = off[i] + blocksum[i >> 10];
    off[i] = v;
    cursor[i] = v;
}

__global__ void csr_fill(const int* __restrict__ src, const int* __restrict__ dst,
                         int* __restrict__ cursor, int* __restrict__ csrsrc, int E) {
    int e = blockIdx.x * blockDim.x + threadIdx.x;
    if (e >= E) return;
    int pos = atomicAdd(&cursor[dst[e]], 1);
    csrsrc[pos] = src[e];
}

// ---------------- per-layer kernels ----------------

#define FMA4(a, s, b) { (a).x += (s) * (b).x; (a).y += (s) * (b).y; (a).z += (s) * (b).z; (a).w += (s) * (b).w; }
__device__ __forceinline__ float dot4(float4 a, float4 b) {
    return a.x * b.x + a.y * b.y + a.z * b.z + a.w * b.w;
}

// 4 nodes x 4 m-cols per thread; fused el/er epilogue (el = feat . al, er = feat . ar)
template <int K, int M>
__global__ void gemm_fused(const float* __restrict__ X, const float* __restrict__ W,
                           const float* __restrict__ al, const float* __restrict__ ar,
                           float* __restrict__ feat, float* __restrict__ el,
                           float* __restrict__ er, int N) {
    constexpr int TPR = M / 4;  // threads per 4-node group
    int idx = blockIdx.x * blockDim.x + threadIdx.x;
    int ng = idx / TPR;
    int tmi = idx % TPR;
    int tm = tmi * 4;
    int n0 = ng * 4;
    if (n0 >= N) return;
    const float* x0 = X + (size_t)n0 * K;

    float4 acc[4];
    #pragma unroll
    for (int j = 0; j < 4; ++j) acc[j] = make_float4(0.f, 0.f, 0.f, 0.f);

    for (int k0 = 0; k0 < K; k0 += 4) {
        float4 xv[4], wv[4];
        #pragma unroll
        for (int j = 0; j < 4; ++j)
            xv[j] = *reinterpret_cast<const float4*>(x0 + (size_t)j * K + k0);
        #pragma unroll
        for (int kk = 0; kk < 4; ++kk)
            wv[kk] = *reinterpret_cast<const float4*>(W + (size_t)(k0 + kk) * M + tm);
        #pragma unroll
        for (int j = 0; j < 4; ++j) {
            FMA4(acc[j], xv[j].x, wv[0]);
            FMA4(acc[j], xv[j].y, wv[1]);
            FMA4(acc[j], xv[j].z, wv[2]);
            FMA4(acc[j], xv[j].w, wv[3]);
        }
    }

    #pragma unroll
    for (int j = 0; j < 4; ++j)
        *reinterpret_cast<float4*>(&feat[(size_t)(n0 + j) * M + tm]) = acc[j];

    // fused attention scores
    float4 a4 = *reinterpret_cast<const float4*>(&al[tm]);
    float4 r4 = *reinterpret_cast<const float4*>(&ar[tm]);
    float elp[4], erp[4];
    #pragma unroll
    for (int j = 0; j < 4; ++j) { elp[j] = dot4(acc[j], a4); erp[j] = dot4(acc[j], r4); }
    #pragma unroll
    for (int o = 1; o < TPR; o <<= 1) {
        #pragma unroll
        for (int j = 0; j < 4; ++j) {
            elp[j] += __shfl_xor(elp[j], o);
            erp[j] += __shfl_xor(erp[j], o);
        }
    }
    if (tmi == 0) {
        #pragma unroll
        for (int j = 0; j < 4; ++j) { el[n0 + j] = elp[j]; er[n0 + j] = erp[j]; }
    }
}

// one wave per node: edge-softmax + weighted gather + bias + act, no atomics
template <int F>
__global__ void gat_agg(const int* __restrict__ off, const int* __restrict__ csrsrc,
                        const float* __restrict__ el, const float* __restrict__ er,
                        const float* __restrict__ feat, const float* __restrict__ bias,
                        float* __restrict__ hout, int N, int do_relu) {
    int node = (blockIdx.x * blockDim.x + threadIdx.x) >> 6;
    int lane = threadIdx.x & 63;
    if (node >= N) return;
    int start = off[node], deg = off[node + 1] - start;
    float ern = er[node];

    // lane-parallel logits; lane i holds edge (start+i) for i<64
    int s0 = 0; float e0 = -1e30f;
    if (lane < deg) { s0 = csrsrc[start + lane]; e0 = leaky(el[s0] + ern); }
    float m = e0;
    for (int i = 64 + lane; i < deg; i += 64) {  // rare tail (deg>64)
        int s = csrsrc[start + i];
        m = fmaxf(m, leaky(el[s] + ern));
    }
    for (int o = 32; o; o >>= 1) m = fmaxf(m, __shfl_xor(m, o));

    float p0 = (lane < deg) ? __expf(e0 - m) : 0.f;
    float ssum = p0;
    for (int i = 64 + lane; i < deg; i += 64) {
        int s = csrsrc[start + i];
        ssum += __expf(leaky(el[s] + ern) - m);
    }
    for (int o = 32; o; o >>= 1) ssum += __shfl_xor(ssum, o);
    float inv = (deg > 0) ? 1.f / ssum : 0.f;

    // gather-accumulate, 4-edge unrolled for memory-level parallelism
    float acc0 = 0.f, acc1 = 0.f;
    int head = (deg < 64) ? deg : 64;
    int i = 0;
    for (; i + 4 <= head; i += 4) {
        float pA = __shfl(p0, i), pB = __shfl(p0, i + 1),
              pC = __shfl(p0, i + 2), pD = __shfl(p0, i + 3);
        int sA = __shfl(s0, i), sB = __shfl(s0, i + 1),
            sC = __shfl(s0, i + 2), sD = __shfl(s0, i + 3);
        const float* fA = feat + (size_t)sA * F;
        const float* fB = feat + (size_t)sB * F;
        const float* fC = feat + (size_t)sC * F;
        const float* fD = feat + (size_t)sD * F;
        float vA = fA[lane], vB = fB[lane], vC = fC[lane], vD = fD[lane];
        if (F == 128) {
            float uA = fA[64 + lane], uB = fB[64 + lane], uC = fC[64 + lane], uD = fD[64 + lane];
            acc1 += pA * uA + pB * uB + pC * uC + pD * uD;
        }
        acc0 += pA * vA + pB * vB + pC * vC + pD * vD;
    }
    for (; i < head; ++i) {
        float p = __shfl(p0, i);
        int sN = __shfl(s0, i);
        acc0 += p * feat[(size_t)sN * F + lane];
        if (F == 128) acc1 += p * feat[(size_t)sN * F + 64 + lane];
    }
    for (i = 64; i < deg; ++i) {  // rare tail: recompute p (broadcast loads)
        int sN = csrsrc[start + i];
        float p = __expf(leaky(el[sN] + ern) - m);
        acc0 += p * feat[(size_t)sN * F + lane];
        if (F == 128) acc1 += p * feat[(size_t)sN * F + 64 + lane];
    }

    float v0 = acc0 * inv + bias[lane];
    if (do_relu) v0 = fmaxf(v0, 0.f);
    hout[(size_t)node * F + lane] = v0;
    if (F == 128) {
        float v1 = acc1 * inv + bias[64 + lane];
        if (do_relu) v1 = fmaxf(v1, 0.f);
        hout[(size_t)node * F + 64 + lane] = v1;
    }
}

// write f32 h to d_out, and per-node link-pred partial scores (F=64 fixed)
__global__ void finalize_h(const float* __restrict__ h, float* __restrict__ outh,
                           const float* __restrict__ lpW, float* __restrict__ s1,
                           float* __restrict__ s2, int N) {
    int wave = (blockIdx.x * blockDim.x + threadIdx.x) >> 6;
    int lane = threadIdx.x & 63;
    if (wave >= N) return;
    float v = h[(size_t)wave * 64 + lane];
    outh[(size_t)wave * 64 + lane] = v;
    float a = v * lpW[lane];
    float b = v * lpW[64 + lane];
    for (int o = 32; o; o >>= 1) { a += __shfl_down(a, o); b += __shfl_down(b, o); }
    if (lane == 0) { s1[wave] = a; s2[wave] = b; }
}

__global__ void scores_k(const int* __restrict__ s, const int* __restrict__ d,
                         const float* __restrict__ s1, const float* __restrict__ s2,
                         const float* __restrict__ lpb, float* __restrict__ out, int E) {
    int i = blockIdx.x * blockDim.x + threadIdx.x;
    if (i >= E) return;
    out[i] = s1[s[i]] + s2[d[i]] + lpb[0];
}

// ---------------- driver ----------------

struct Scratch {
    float* feat; float* hA; float* hB;
    float* el; float* er; float* s1; float* s2;
    int* cnt; int* off; int* cursor; int* csrsrc; int* blocksum;
};

template <int K, int M>
static void run_layer(const float* hin, const float* W, const float* al,
                      const float* ar, const float* b, bool relu,
                      float* hout, const Scratch& S, hipStream_t stream) {
    const int N = NN;
    constexpr int TPR = M / 4;
    int tthreads = (N / 4) * TPR;
    gemm_fused<K, M><<<(tthreads + 255) / 256, 256, 0, stream>>>(hin, W, al, ar,
                                                                 S.feat, S.el, S.er, N);
    gat_agg<M><<<(N + 3) / 4, 256, 0, stream>>>(S.off, S.csrsrc, S.el, S.er, S.feat, b,
                                                hout, N, relu ? 1 : 0);
}

extern "C" void kernel_launch(void* const* d_in, const int* in_sizes, int n_in,
                              void* d_out, int out_size, void* d_ws, size_t ws_size,
                              hipStream_t stream) {
    const float* x   = (const float*)d_in[0];
    const float* W1  = (const float*)d_in[1];
    const float* al1 = (const float*)d_in[2];
    const float* ar1 = (const float*)d_in[3];
    const float* b1  = (const float*)d_in[4];
    const float* W2  = (const float*)d_in[5];
    const float* al2 = (const float*)d_in[6];
    const float* ar2 = (const float*)d_in[7];
    const float* b2  = (const float*)d_in[8];
    const float* W3  = (const float*)d_in[9];
    const float* al3 = (const float*)d_in[10];
    const float* ar3 = (const float*)d_in[11];
    const float* b3  = (const float*)d_in[12];
    const float* lpW = (const float*)d_in[13];
    const float* lpb = (const float*)d_in[14];
    const int* src  = (const int*)d_in[15];
    const int* dst  = (const int*)d_in[16];
    const int* nsrc = (const int*)d_in[17];
    const int* ndst = (const int*)d_in[18];

    char* w = (char*)d_ws;
    Scratch S;
    S.feat     = (float*)w; w += (size_t)NN * 128 * 4;
    S.hA       = (float*)w; w += (size_t)NN * 64 * 4;
    S.hB       = (float*)w; w += (size_t)NN * 128 * 4;
    S.el       = (float*)w; w += (size_t)NN * 4;
    S.er       = (float*)w; w += (size_t)NN * 4;
    S.s1       = (float*)w; w += (size_t)NN * 4;
    S.s2       = (float*)w; w += (size_t)NN * 4;
    S.cnt      = (int*)w;   w += (size_t)NN * 4;
    S.off      = (int*)w;   w += (size_t)(NN + 1) * 4;
    S.cursor   = (int*)w;   w += (size_t)NN * 4;
    S.csrsrc   = (int*)w;   w += (size_t)NE * 4;
    S.blocksum = (int*)w;   w += 64 * 4;

    // build dst-CSR once; reused by all 3 layers
    const int NB = (NN + 1023) / 1024;  // 49
    hipMemsetAsync(S.cnt, 0, (size_t)NN * 4, stream);
    hist_k<<<(NE + 255) / 256, 256, 0, stream>>>(dst, S.cnt, NE);
    scan_blocks<<<NB, 1024, 0, stream>>>(S.cnt, S.off, S.blocksum, NN);
    scan_sums<<<1, 64, 0, stream>>>(S.blocksum, NB, &S.off[NN]);
    scan_apply<<<(NN + 255) / 256, 256, 0, stream>>>(S.off, S.blocksum, S.cursor, NN);
    csr_fill<<<(NE + 255) / 256, 256, 0, stream>>>(src, dst, S.cursor, S.csrsrc, NE);

    // layer 1: x[50000,128] @ W1[128,64] -> hA, relu
    run_layer<128, 64>(x, W1, al1, ar1, b1, true, S.hA, S, stream);
    // layer 2: hA[50000,64] @ W2[64,128] -> hB, relu
    run_layer<64, 128>(S.hA, W2, al2, ar2, b2, true, S.hB, S, stream);
    // layer 3: hB[50000,128] @ W3[128,64] -> hA (reuse), no relu
    run_layer<128, 64>(S.hB, W3, al3, ar3, b3, false, S.hA, S, stream);

    float* out_h   = (float*)d_out;
    float* out_pos = out_h + (size_t)NN * 64;
    float* out_neg = out_pos + NE;

    finalize_h<<<(NN + 3) / 4, 256, 0, stream>>>(S.hA, out_h, lpW, S.s1, S.s2, NN);
    scores_k<<<(NE + 255) / 256, 256, 0, stream>>>(src, dst, S.s1, S.s2, lpb, out_pos, NE);
    scores_k<<<(NE + 255) / 256, 256, 0, stream>>>(nsrc, ndst, S.s1, S.s2, lpb, out_neg, NE);
}

// Round 6
// 323.467 us; speedup vs baseline: 4.7011x; 1.0758x over previous
//
#include <hip/hip_runtime.h>
#include <hip/hip_bf16.h>

#define NN 50000
#define NE 800000

typedef unsigned short ushort_t;
typedef unsigned int uint_t;

__device__ __forceinline__ float leaky(float v) { return (v >= 0.f) ? v : 0.2f * v; }
__device__ __forceinline__ ushort_t f2bf(float f) {
    __hip_bfloat16 h = __float2bfloat16(f);
    return *reinterpret_cast<ushort_t*>(&h);
}
__device__ __forceinline__ float bf_lo(uint_t v) { return __uint_as_float(v << 16); }
__device__ __forceinline__ float bf_hi(uint_t v) { return __uint_as_float(v & 0xFFFF0000u); }
__device__ __forceinline__ float bf_s(ushort_t u) { return __uint_as_float((uint_t)u << 16); }

// ---------------- CSR build (graph is identical for all 3 layers) ----------------

__global__ void hist_k(const int* __restrict__ dst, int* __restrict__ cnt, int E) {
    int e = blockIdx.x * blockDim.x + threadIdx.x;
    if (e < E) atomicAdd(&cnt[dst[e]], 1);
}

__global__ void scan_blocks(const int* __restrict__ cnt, int* __restrict__ off,
                            int* __restrict__ blocksum, int n) {
    __shared__ int ws[16];
    int t = threadIdx.x;
    int idx = blockIdx.x * 1024 + t;
    int lane = t & 63, w = t >> 6;
    int v = (idx < n) ? cnt[idx] : 0;
    int sc = v;
    for (int o = 1; o < 64; o <<= 1) {
        int x = __shfl_up(sc, o);
        if (lane >= o) sc += x;
    }
    if (lane == 63) ws[w] = sc;
    __syncthreads();
    if (t == 0) {
        int run = 0;
        #pragma unroll
        for (int i = 0; i < 16; ++i) { int tmp = ws[i]; ws[i] = run; run += tmp; }
        blocksum[blockIdx.x] = run;
    }
    __syncthreads();
    if (idx < n) off[idx] = ws[w] + sc - v;
}

__global__ void scan_sums(int* __restrict__ blocksum, int nb, int* __restrict__ off_end) {
    int t = threadIdx.x;  // 64 threads
    int v = (t < nb) ? blocksum[t] : 0;
    int sc = v;
    for (int o = 1; o < 64; o <<= 1) {
        int x = __shfl_up(sc, o);
        if (t >= o) sc += x;
    }
    if (t < nb) blocksum[t] = sc - v;
    if (t == 63) *off_end = sc;
}

__global__ void scan_apply(int* __restrict__ off, const int* __restrict__ blocksum,
                           int* __restrict__ cursor, int n) {
    int i = blockIdx.x * blockDim.x + threadIdx.x;
    if (i >= n) return;
    int v = off[i] + blocksum[i >> 10];
    off[i] = v;
    cursor[i] = v;
}

__global__ void csr_fill(const int* __restrict__ src, const int* __restrict__ dst,
                         int* __restrict__ cursor, int* __restrict__ csrsrc, int E) {
    int e = blockIdx.x * blockDim.x + threadIdx.x;
    if (e >= E) return;
    int pos = atomicAdd(&cursor[dst[e]], 1);
    csrsrc[pos] = src[e];
}

// ---------------- per-layer kernels ----------------

#define FMA4(a, s, b) { (a).x += (s) * (b).x; (a).y += (s) * (b).y; (a).z += (s) * (b).z; (a).w += (s) * (b).w; }
__device__ __forceinline__ float dot4(float4 a, float4 b) {
    return a.x * b.x + a.y * b.y + a.z * b.z + a.w * b.w;
}

// 4 nodes x 4 m-cols per thread; fused el/er epilogue. BF: store feat as packed bf16.
template <int K, int M, bool BF>
__global__ void gemm_fused(const float* __restrict__ X, const float* __restrict__ W,
                           const float* __restrict__ al, const float* __restrict__ ar,
                           float* __restrict__ feat, ushort_t* __restrict__ featbf,
                           float* __restrict__ el, float* __restrict__ er, int N) {
    constexpr int TPR = M / 4;
    int idx = blockIdx.x * blockDim.x + threadIdx.x;
    int ng = idx / TPR;
    int tmi = idx % TPR;
    int tm = tmi * 4;
    int n0 = ng * 4;
    if (n0 >= N) return;
    const float* x0 = X + (size_t)n0 * K;

    float4 acc[4];
    #pragma unroll
    for (int j = 0; j < 4; ++j) acc[j] = make_float4(0.f, 0.f, 0.f, 0.f);

    for (int k0 = 0; k0 < K; k0 += 4) {
        float4 xv[4], wv[4];
        #pragma unroll
        for (int j = 0; j < 4; ++j)
            xv[j] = *reinterpret_cast<const float4*>(x0 + (size_t)j * K + k0);
        #pragma unroll
        for (int kk = 0; kk < 4; ++kk)
            wv[kk] = *reinterpret_cast<const float4*>(W + (size_t)(k0 + kk) * M + tm);
        #pragma unroll
        for (int j = 0; j < 4; ++j) {
            FMA4(acc[j], xv[j].x, wv[0]);
            FMA4(acc[j], xv[j].y, wv[1]);
            FMA4(acc[j], xv[j].z, wv[2]);
            FMA4(acc[j], xv[j].w, wv[3]);
        }
    }

    if (BF) {
        #pragma unroll
        for (int j = 0; j < 4; ++j) {
            uint2 pr;
            pr.x = ((uint_t)f2bf(acc[j].y) << 16) | (uint_t)f2bf(acc[j].x);
            pr.y = ((uint_t)f2bf(acc[j].w) << 16) | (uint_t)f2bf(acc[j].z);
            *reinterpret_cast<uint2*>(featbf + (size_t)(n0 + j) * M + tm) = pr;
        }
    } else {
        #pragma unroll
        for (int j = 0; j < 4; ++j)
            *reinterpret_cast<float4*>(&feat[(size_t)(n0 + j) * M + tm]) = acc[j];
    }

    // fused attention scores (always from fp32 accumulators)
    float4 a4 = *reinterpret_cast<const float4*>(&al[tm]);
    float4 r4 = *reinterpret_cast<const float4*>(&ar[tm]);
    float elp[4], erp[4];
    #pragma unroll
    for (int j = 0; j < 4; ++j) { elp[j] = dot4(acc[j], a4); erp[j] = dot4(acc[j], r4); }
    #pragma unroll
    for (int o = 1; o < TPR; o <<= 1) {
        #pragma unroll
        for (int j = 0; j < 4; ++j) {
            elp[j] += __shfl_xor(elp[j], o);
            erp[j] += __shfl_xor(erp[j], o);
        }
    }
    if (tmi == 0) {
        #pragma unroll
        for (int j = 0; j < 4; ++j) { el[n0 + j] = elp[j]; er[n0 + j] = erp[j]; }
    }
}

// one wave per node: edge-softmax + weighted gather + bias + act, no atomics
template <int F, bool BF>
__global__ void gat_agg(const int* __restrict__ off, const int* __restrict__ csrsrc,
                        const float* __restrict__ el, const float* __restrict__ er,
                        const float* __restrict__ feat, const ushort_t* __restrict__ featbf,
                        const float* __restrict__ bias,
                        float* __restrict__ hout, int N, int do_relu) {
    int node = (blockIdx.x * blockDim.x + threadIdx.x) >> 6;
    int lane = threadIdx.x & 63;
    if (node >= N) return;
    int start = off[node], deg = off[node + 1] - start;
    float ern = er[node];

    int s0 = 0; float e0 = -1e30f;
    if (lane < deg) { s0 = csrsrc[start + lane]; e0 = leaky(el[s0] + ern); }
    float m = e0;
    for (int i = 64 + lane; i < deg; i += 64) {
        int s = csrsrc[start + i];
        m = fmaxf(m, leaky(el[s] + ern));
    }
    for (int o = 32; o; o >>= 1) m = fmaxf(m, __shfl_xor(m, o));

    float p0 = (lane < deg) ? __expf(e0 - m) : 0.f;
    float ssum = p0;
    for (int i = 64 + lane; i < deg; i += 64) {
        int s = csrsrc[start + i];
        ssum += __expf(leaky(el[s] + ern) - m);
    }
    for (int o = 32; o; o >>= 1) ssum += __shfl_xor(ssum, o);
    float inv = (deg > 0) ? 1.f / ssum : 0.f;

    // gather-accumulate, 4-edge unrolled
    float acc0 = 0.f, acc1 = 0.f;
    int head = (deg < 64) ? deg : 64;
    int i = 0;
    for (; i + 4 <= head; i += 4) {
        float pA = __shfl(p0, i), pB = __shfl(p0, i + 1),
              pC = __shfl(p0, i + 2), pD = __shfl(p0, i + 3);
        int sA = __shfl(s0, i), sB = __shfl(s0, i + 1),
            sC = __shfl(s0, i + 2), sD = __shfl(s0, i + 3);
        if (BF) {
            if (F == 128) {
                uint_t vA = ((const uint_t*)(featbf + (size_t)sA * F))[lane];
                uint_t vB = ((const uint_t*)(featbf + (size_t)sB * F))[lane];
                uint_t vC = ((const uint_t*)(featbf + (size_t)sC * F))[lane];
                uint_t vD = ((const uint_t*)(featbf + (size_t)sD * F))[lane];
                acc0 += pA * bf_lo(vA) + pB * bf_lo(vB) + pC * bf_lo(vC) + pD * bf_lo(vD);
                acc1 += pA * bf_hi(vA) + pB * bf_hi(vB) + pC * bf_hi(vC) + pD * bf_hi(vD);
            } else {
                ushort_t uA = featbf[(size_t)sA * F + lane];
                ushort_t uB = featbf[(size_t)sB * F + lane];
                ushort_t uC = featbf[(size_t)sC * F + lane];
                ushort_t uD = featbf[(size_t)sD * F + lane];
                acc0 += pA * bf_s(uA) + pB * bf_s(uB) + pC * bf_s(uC) + pD * bf_s(uD);
            }
        } else {
            const float* fA = feat + (size_t)sA * F;
            const float* fB = feat + (size_t)sB * F;
            const float* fC = feat + (size_t)sC * F;
            const float* fD = feat + (size_t)sD * F;
            float vA = fA[lane], vB = fB[lane], vC = fC[lane], vD = fD[lane];
            if (F == 128) {
                float uA = fA[64 + lane], uB = fB[64 + lane], uC = fC[64 + lane], uD = fD[64 + lane];
                acc1 += pA * uA + pB * uB + pC * uC + pD * uD;
            }
            acc0 += pA * vA + pB * vB + pC * vC + pD * vD;
        }
    }
    for (; i < head; ++i) {
        float p = __shfl(p0, i);
        int sN = __shfl(s0, i);
        if (BF) {
            if (F == 128) {
                uint_t v = ((const uint_t*)(featbf + (size_t)sN * F))[lane];
                acc0 += p * bf_lo(v); acc1 += p * bf_hi(v);
            } else {
                acc0 += p * bf_s(featbf[(size_t)sN * F + lane]);
            }
        } else {
            acc0 += p * feat[(size_t)sN * F + lane];
            if (F == 128) acc1 += p * feat[(size_t)sN * F + 64 + lane];
        }
    }
    for (i = 64; i < deg; ++i) {
        int sN = csrsrc[start + i];
        float p = __expf(leaky(el[sN] + ern) - m);
        if (BF) {
            if (F == 128) {
                uint_t v = ((const uint_t*)(featbf + (size_t)sN * F))[lane];
                acc0 += p * bf_lo(v); acc1 += p * bf_hi(v);
            } else {
                acc0 += p * bf_s(featbf[(size_t)sN * F + lane]);
            }
        } else {
            acc0 += p * feat[(size_t)sN * F + lane];
            if (F == 128) acc1 += p * feat[(size_t)sN * F + 64 + lane];
        }
    }

    if (BF && F == 128) {
        // lane holds features 2*lane, 2*lane+1
        float2 b2 = *reinterpret_cast<const float2*>(&bias[2 * lane]);
        float v0 = acc0 * inv + b2.x;
        float v1 = acc1 * inv + b2.y;
        if (do_relu) { v0 = fmaxf(v0, 0.f); v1 = fmaxf(v1, 0.f); }
        *reinterpret_cast<float2*>(&hout[(size_t)node * F + 2 * lane]) = make_float2(v0, v1);
    } else {
        float v0 = acc0 * inv + bias[lane];
        if (do_relu) v0 = fmaxf(v0, 0.f);
        hout[(size_t)node * F + lane] = v0;
        if (!BF && F == 128) {
            float v1 = acc1 * inv + bias[64 + lane];
            if (do_relu) v1 = fmaxf(v1, 0.f);
            hout[(size_t)node * F + 64 + lane] = v1;
        }
    }
}

// write f32 h to d_out, and per-node link-pred partial scores (F=64 fixed)
__global__ void finalize_h(const float* __restrict__ h, float* __restrict__ outh,
                           const float* __restrict__ lpW, float* __restrict__ s1,
                           float* __restrict__ s2, int N) {
    int wave = (blockIdx.x * blockDim.x + threadIdx.x) >> 6;
    int lane = threadIdx.x & 63;
    if (wave >= N) return;
    float v = h[(size_t)wave * 64 + lane];
    outh[(size_t)wave * 64 + lane] = v;
    float a = v * lpW[lane];
    float b = v * lpW[64 + lane];
    for (int o = 32; o; o >>= 1) { a += __shfl_down(a, o); b += __shfl_down(b, o); }
    if (lane == 0) { s1[wave] = a; s2[wave] = b; }
}

__global__ void scores_k(const int* __restrict__ s, const int* __restrict__ d,
                         const float* __restrict__ s1, const float* __restrict__ s2,
                         const float* __restrict__ lpb, float* __restrict__ out, int E) {
    int i = blockIdx.x * blockDim.x + threadIdx.x;
    if (i >= E) return;
    out[i] = s1[s[i]] + s2[d[i]] + lpb[0];
}

// ---------------- driver ----------------

struct Scratch {
    float* feat; ushort_t* featbf; float* hA; float* hB;
    float* el; float* er; float* s1; float* s2;
    int* cnt; int* off; int* cursor; int* csrsrc; int* blocksum;
};

template <int K, int M, bool BF>
static void run_layer(const float* hin, const float* W, const float* al,
                      const float* ar, const float* b, bool relu,
                      float* hout, const Scratch& S, hipStream_t stream) {
    const int N = NN;
    constexpr int TPR = M / 4;
    int tthreads = (N / 4) * TPR;
    gemm_fused<K, M, BF><<<(tthreads + 255) / 256, 256, 0, stream>>>(
        hin, W, al, ar, S.feat, S.featbf, S.el, S.er, N);
    gat_agg<M, BF><<<(N + 3) / 4, 256, 0, stream>>>(S.off, S.csrsrc, S.el, S.er,
                                                    S.feat, S.featbf, b, hout, N, relu ? 1 : 0);
}

extern "C" void kernel_launch(void* const* d_in, const int* in_sizes, int n_in,
                              void* d_out, int out_size, void* d_ws, size_t ws_size,
                              hipStream_t stream) {
    const float* x   = (const float*)d_in[0];
    const float* W1  = (const float*)d_in[1];
    const float* al1 = (const float*)d_in[2];
    const float* ar1 = (const float*)d_in[3];
    const float* b1  = (const float*)d_in[4];
    const float* W2  = (const float*)d_in[5];
    const float* al2 = (const float*)d_in[6];
    const float* ar2 = (const float*)d_in[7];
    const float* b2  = (const float*)d_in[8];
    const float* W3  = (const float*)d_in[9];
    const float* al3 = (const float*)d_in[10];
    const float* ar3 = (const float*)d_in[11];
    const float* b3  = (const float*)d_in[12];
    const float* lpW = (const float*)d_in[13];
    const float* lpb = (const float*)d_in[14];
    const int* src  = (const int*)d_in[15];
    const int* dst  = (const int*)d_in[16];
    const int* nsrc = (const int*)d_in[17];
    const int* ndst = (const int*)d_in[18];

    char* w = (char*)d_ws;
    Scratch S;
    S.feat     = (float*)w;    w += (size_t)NN * 128 * 4;
    S.featbf   = (ushort_t*)w; w += (size_t)NN * 128 * 2;
    S.hA       = (float*)w;    w += (size_t)NN * 64 * 4;
    S.hB       = (float*)w;    w += (size_t)NN * 128 * 4;
    S.el       = (float*)w;    w += (size_t)NN * 4;
    S.er       = (float*)w;    w += (size_t)NN * 4;
    S.s1       = (float*)w;    w += (size_t)NN * 4;
    S.s2       = (float*)w;    w += (size_t)NN * 4;
    S.cnt      = (int*)w;      w += (size_t)NN * 4;
    S.off      = (int*)w;      w += (size_t)(NN + 1) * 4;
    S.cursor   = (int*)w;      w += (size_t)NN * 4;
    S.csrsrc   = (int*)w;      w += (size_t)NE * 4;
    S.blocksum = (int*)w;      w += 64 * 4;

    // build dst-CSR once; reused by all 3 layers
    const int NB = (NN + 1023) / 1024;  // 49
    hipMemsetAsync(S.cnt, 0, (size_t)NN * 4, stream);
    hist_k<<<(NE + 255) / 256, 256, 0, stream>>>(dst, S.cnt, NE);
    scan_blocks<<<NB, 1024, 0, stream>>>(S.cnt, S.off, S.blocksum, NN);
    scan_sums<<<1, 64, 0, stream>>>(S.blocksum, NB, &S.off[NN]);
    scan_apply<<<(NN + 255) / 256, 256, 0, stream>>>(S.off, S.blocksum, S.cursor, NN);
    csr_fill<<<(NE + 255) / 256, 256, 0, stream>>>(src, dst, S.cursor, S.csrsrc, NE);

    // layer 1: x[50000,128] @ W1[128,64] -> hA, relu   (bf16 gather)
    run_layer<128, 64, true>(x, W1, al1, ar1, b1, true, S.hA, S, stream);
    // layer 2: hA[50000,64] @ W2[64,128] -> hB, relu   (bf16 gather)
    run_layer<64, 128, true>(S.hA, W2, al2, ar2, b2, true, S.hB, S, stream);
    // layer 3: hB[50000,128] @ W3[128,64] -> hA, no relu  (fp32 gather: output layer)
    run_layer<128, 64, false>(S.hB, W3, al3, ar3, b3, false, S.hA, S, stream);

    float* out_h   = (float*)d_out;
    float* out_pos = out_h + (size_t)NN * 64;
    float* out_neg = out_pos + NE;

    finalize_h<<<(NN + 3) / 4, 256, 0, stream>>>(S.hA, out_h, lpW, S.s1, S.s2, NN);
    scores_k<<<(NE + 255) / 256, 256, 0, stream>>>(src, dst, S.s1, S.s2, lpb, out_pos, NE);
    scores_k<<<(NE + 255) / 256, 256, 0, stream>>>(nsrc, ndst, S.s1, S.s2, lpb, out_neg, NE);
}

// Round 7
// 280.007 us; speedup vs baseline: 5.4308x; 1.1552x over previous
//
#include <hip/hip_runtime.h>
#include <hip/hip_bf16.h>

#define NN 50000
#define NE 800000
#define NBKT 196        // ceil(NN/256) buckets of 256 nodes
#define NT 200          // partition tiles
#define TILE 4000       // NE/NT exactly

typedef unsigned short ushort_t;
typedef unsigned int uint_t;

__device__ __forceinline__ float leaky(float v) { return (v >= 0.f) ? v : 0.2f * v; }
__device__ __forceinline__ ushort_t f2bf(float f) {
    __hip_bfloat16 h = __float2bfloat16(f);
    return *reinterpret_cast<ushort_t*>(&h);
}
__device__ __forceinline__ float bf_lo(uint_t v) { return __uint_as_float(v << 16); }
__device__ __forceinline__ float bf_hi(uint_t v) { return __uint_as_float(v & 0xFFFF0000u); }
__device__ __forceinline__ float bf_s(ushort_t u) { return __uint_as_float((uint_t)u << 16); }

// ---------------- CSR build: bucketed counting sort (no global atomics) ----------------

// P1: per-tile bucket histogram (LDS)
__global__ void part_hist(const int* __restrict__ dst, uint_t* __restrict__ gh) {
    __shared__ uint_t h[NBKT];
    int t = blockIdx.x, tid = threadIdx.x;
    for (int i = tid; i < NBKT; i += 256) h[i] = 0;
    __syncthreads();
    int e0 = t * TILE;
    for (int i = tid; i < TILE; i += 256)
        atomicAdd(&h[((uint_t)dst[e0 + i]) >> 8], 1u);
    __syncthreads();
    for (int i = tid; i < NBKT; i += 256) gh[t * NBKT + i] = h[i];
}

// P2: column-scan gh over tiles (thread b owns bucket b), then scan bucket totals
__global__ void scan_gh(uint_t* __restrict__ gh, uint_t* __restrict__ bucketbase) {
    int b = threadIdx.x;  // 256 threads
    uint_t run = 0;
    if (b < NBKT) {
        for (int t = 0; t < NT; ++t) {
            uint_t v = gh[t * NBKT + b];
            gh[t * NBKT + b] = run;
            run += v;
        }
    }
    int lane = b & 63, w = b >> 6;
    uint_t sc = run;
    for (int o = 1; o < 64; o <<= 1) {
        uint_t x = __shfl_up(sc, o);
        if (lane >= o) sc += x;
    }
    __shared__ uint_t ws4[4];
    if (lane == 63) ws4[w] = sc;
    __syncthreads();
    if (b == 0) { uint_t r = 0; for (int i = 0; i < 4; ++i) { uint_t tmp = ws4[i]; ws4[i] = r; r += tmp; } }
    __syncthreads();
    uint_t excl = ws4[w] + sc - run;
    if (b < NBKT) {
        bucketbase[b] = excl;
        for (int t = 0; t < NT; ++t) gh[t * NBKT + b] += excl;
    }
    if (b == NBKT - 1) bucketbase[NBKT] = excl + run;
}

// P3: scatter (src,dst) pairs into bucket-contiguous pairbuf via LDS cursors
__global__ void part_scatter(const int* __restrict__ src, const int* __restrict__ dst,
                             const uint_t* __restrict__ gh, int2* __restrict__ pairbuf) {
    __shared__ uint_t cur[NBKT];
    int t = blockIdx.x, tid = threadIdx.x;
    for (int i = tid; i < NBKT; i += 256) cur[i] = gh[t * NBKT + i];
    __syncthreads();
    int e0 = t * TILE;
    for (int i = tid; i < TILE; i += 256) {
        int d = dst[e0 + i], s = src[e0 + i];
        uint_t pos = atomicAdd(&cur[((uint_t)d) >> 8], 1u);
        pairbuf[pos] = make_int2(s, d);
    }
}

// P4: per-bucket per-node count + scan -> off[]; LDS cursors -> csrsrc (hot 16KB region)
__global__ void bucket_csr(const int2* __restrict__ pairbuf, const uint_t* __restrict__ bucketbase,
                           int* __restrict__ off, int* __restrict__ csrsrc) {
    int b = blockIdx.x, tid = threadIdx.x;
    uint_t eb0 = bucketbase[b], m = bucketbase[b + 1] - eb0;
    __shared__ uint_t cnt[256];
    __shared__ uint_t ws4[4];
    cnt[tid] = 0;
    __syncthreads();
    for (uint_t i = tid; i < m; i += 256)
        atomicAdd(&cnt[pairbuf[eb0 + i].y & 255], 1u);
    __syncthreads();
    uint_t v = cnt[tid];
    int lane = tid & 63, w = tid >> 6;
    uint_t sc = v;
    for (int o = 1; o < 64; o <<= 1) {
        uint_t x = __shfl_up(sc, o);
        if (lane >= o) sc += x;
    }
    if (lane == 63) ws4[w] = sc;
    __syncthreads();
    if (tid == 0) { uint_t r = 0; for (int i = 0; i < 4; ++i) { uint_t tmp = ws4[i]; ws4[i] = r; r += tmp; } }
    __syncthreads();
    uint_t excl = ws4[w] + sc - v;
    int node = b * 256 + tid;
    if (node < NN) off[node] = (int)(eb0 + excl);
    if (b == 0 && tid == 0) off[NN] = NE;
    __syncthreads();
    cnt[tid] = eb0 + excl;  // reuse as cursor
    __syncthreads();
    for (uint_t i = tid; i < m; i += 256) {
        int2 p = pairbuf[eb0 + i];
        uint_t pos = atomicAdd(&cnt[p.y & 255], 1u);
        csrsrc[pos] = p.x;
    }
}

// ---------------- per-layer kernels (unchanged from round 6) ----------------

#define FMA4(a, s, b) { (a).x += (s) * (b).x; (a).y += (s) * (b).y; (a).z += (s) * (b).z; (a).w += (s) * (b).w; }
__device__ __forceinline__ float dot4(float4 a, float4 b) {
    return a.x * b.x + a.y * b.y + a.z * b.z + a.w * b.w;
}

template <int K, int M, bool BF>
__global__ void gemm_fused(const float* __restrict__ X, const float* __restrict__ W,
                           const float* __restrict__ al, const float* __restrict__ ar,
                           float* __restrict__ feat, ushort_t* __restrict__ featbf,
                           float* __restrict__ el, float* __restrict__ er, int N) {
    constexpr int TPR = M / 4;
    int idx = blockIdx.x * blockDim.x + threadIdx.x;
    int ng = idx / TPR;
    int tmi = idx % TPR;
    int tm = tmi * 4;
    int n0 = ng * 4;
    if (n0 >= N) return;
    const float* x0 = X + (size_t)n0 * K;

    float4 acc[4];
    #pragma unroll
    for (int j = 0; j < 4; ++j) acc[j] = make_float4(0.f, 0.f, 0.f, 0.f);

    for (int k0 = 0; k0 < K; k0 += 4) {
        float4 xv[4], wv[4];
        #pragma unroll
        for (int j = 0; j < 4; ++j)
            xv[j] = *reinterpret_cast<const float4*>(x0 + (size_t)j * K + k0);
        #pragma unroll
        for (int kk = 0; kk < 4; ++kk)
            wv[kk] = *reinterpret_cast<const float4*>(W + (size_t)(k0 + kk) * M + tm);
        #pragma unroll
        for (int j = 0; j < 4; ++j) {
            FMA4(acc[j], xv[j].x, wv[0]);
            FMA4(acc[j], xv[j].y, wv[1]);
            FMA4(acc[j], xv[j].z, wv[2]);
            FMA4(acc[j], xv[j].w, wv[3]);
        }
    }

    if (BF) {
        #pragma unroll
        for (int j = 0; j < 4; ++j) {
            uint2 pr;
            pr.x = ((uint_t)f2bf(acc[j].y) << 16) | (uint_t)f2bf(acc[j].x);
            pr.y = ((uint_t)f2bf(acc[j].w) << 16) | (uint_t)f2bf(acc[j].z);
            *reinterpret_cast<uint2*>(featbf + (size_t)(n0 + j) * M + tm) = pr;
        }
    } else {
        #pragma unroll
        for (int j = 0; j < 4; ++j)
            *reinterpret_cast<float4*>(&feat[(size_t)(n0 + j) * M + tm]) = acc[j];
    }

    float4 a4 = *reinterpret_cast<const float4*>(&al[tm]);
    float4 r4 = *reinterpret_cast<const float4*>(&ar[tm]);
    float elp[4], erp[4];
    #pragma unroll
    for (int j = 0; j < 4; ++j) { elp[j] = dot4(acc[j], a4); erp[j] = dot4(acc[j], r4); }
    #pragma unroll
    for (int o = 1; o < TPR; o <<= 1) {
        #pragma unroll
        for (int j = 0; j < 4; ++j) {
            elp[j] += __shfl_xor(elp[j], o);
            erp[j] += __shfl_xor(erp[j], o);
        }
    }
    if (tmi == 0) {
        #pragma unroll
        for (int j = 0; j < 4; ++j) { el[n0 + j] = elp[j]; er[n0 + j] = erp[j]; }
    }
}

template <int F, bool BF>
__global__ void gat_agg(const int* __restrict__ off, const int* __restrict__ csrsrc,
                        const float* __restrict__ el, const float* __restrict__ er,
                        const float* __restrict__ feat, const ushort_t* __restrict__ featbf,
                        const float* __restrict__ bias,
                        float* __restrict__ hout, int N, int do_relu) {
    int node = (blockIdx.x * blockDim.x + threadIdx.x) >> 6;
    int lane = threadIdx.x & 63;
    if (node >= N) return;
    int start = off[node], deg = off[node + 1] - start;
    float ern = er[node];

    int s0 = 0; float e0 = -1e30f;
    if (lane < deg) { s0 = csrsrc[start + lane]; e0 = leaky(el[s0] + ern); }
    float m = e0;
    for (int i = 64 + lane; i < deg; i += 64) {
        int s = csrsrc[start + i];
        m = fmaxf(m, leaky(el[s] + ern));
    }
    for (int o = 32; o; o >>= 1) m = fmaxf(m, __shfl_xor(m, o));

    float p0 = (lane < deg) ? __expf(e0 - m) : 0.f;
    float ssum = p0;
    for (int i = 64 + lane; i < deg; i += 64) {
        int s = csrsrc[start + i];
        ssum += __expf(leaky(el[s] + ern) - m);
    }
    for (int o = 32; o; o >>= 1) ssum += __shfl_xor(ssum, o);
    float inv = (deg > 0) ? 1.f / ssum : 0.f;

    float acc0 = 0.f, acc1 = 0.f;
    int head = (deg < 64) ? deg : 64;
    int i = 0;
    for (; i + 4 <= head; i += 4) {
        float pA = __shfl(p0, i), pB = __shfl(p0, i + 1),
              pC = __shfl(p0, i + 2), pD = __shfl(p0, i + 3);
        int sA = __shfl(s0, i), sB = __shfl(s0, i + 1),
            sC = __shfl(s0, i + 2), sD = __shfl(s0, i + 3);
        if (BF) {
            if (F == 128) {
                uint_t vA = ((const uint_t*)(featbf + (size_t)sA * F))[lane];
                uint_t vB = ((const uint_t*)(featbf + (size_t)sB * F))[lane];
                uint_t vC = ((const uint_t*)(featbf + (size_t)sC * F))[lane];
                uint_t vD = ((const uint_t*)(featbf + (size_t)sD * F))[lane];
                acc0 += pA * bf_lo(vA) + pB * bf_lo(vB) + pC * bf_lo(vC) + pD * bf_lo(vD);
                acc1 += pA * bf_hi(vA) + pB * bf_hi(vB) + pC * bf_hi(vC) + pD * bf_hi(vD);
            } else {
                ushort_t uA = featbf[(size_t)sA * F + lane];
                ushort_t uB = featbf[(size_t)sB * F + lane];
                ushort_t uC = featbf[(size_t)sC * F + lane];
                ushort_t uD = featbf[(size_t)sD * F + lane];
                acc0 += pA * bf_s(uA) + pB * bf_s(uB) + pC * bf_s(uC) + pD * bf_s(uD);
            }
        } else {
            const float* fA = feat + (size_t)sA * F;
            const float* fB = feat + (size_t)sB * F;
            const float* fC = feat + (size_t)sC * F;
            const float* fD = feat + (size_t)sD * F;
            float vA = fA[lane], vB = fB[lane], vC = fC[lane], vD = fD[lane];
            if (F == 128) {
                float uA = fA[64 + lane], uB = fB[64 + lane], uC = fC[64 + lane], uD = fD[64 + lane];
                acc1 += pA * uA + pB * uB + pC * uC + pD * uD;
            }
            acc0 += pA * vA + pB * vB + pC * vC + pD * vD;
        }
    }
    for (; i < head; ++i) {
        float p = __shfl(p0, i);
        int sN = __shfl(s0, i);
        if (BF) {
            if (F == 128) {
                uint_t v = ((const uint_t*)(featbf + (size_t)sN * F))[lane];
                acc0 += p * bf_lo(v); acc1 += p * bf_hi(v);
            } else {
                acc0 += p * bf_s(featbf[(size_t)sN * F + lane]);
            }
        } else {
            acc0 += p * feat[(size_t)sN * F + lane];
            if (F == 128) acc1 += p * feat[(size_t)sN * F + 64 + lane];
        }
    }
    for (i = 64; i < deg; ++i) {
        int sN = csrsrc[start + i];
        float p = __expf(leaky(el[sN] + ern) - m);
        if (BF) {
            if (F == 128) {
                uint_t v = ((const uint_t*)(featbf + (size_t)sN * F))[lane];
                acc0 += p * bf_lo(v); acc1 += p * bf_hi(v);
            } else {
                acc0 += p * bf_s(featbf[(size_t)sN * F + lane]);
            }
        } else {
            acc0 += p * feat[(size_t)sN * F + lane];
            if (F == 128) acc1 += p * feat[(size_t)sN * F + 64 + lane];
        }
    }

    if (BF && F == 128) {
        float2 b2 = *reinterpret_cast<const float2*>(&bias[2 * lane]);
        float v0 = acc0 * inv + b2.x;
        float v1 = acc1 * inv + b2.y;
        if (do_relu) { v0 = fmaxf(v0, 0.f); v1 = fmaxf(v1, 0.f); }
        *reinterpret_cast<float2*>(&hout[(size_t)node * F + 2 * lane]) = make_float2(v0, v1);
    } else {
        float v0 = acc0 * inv + bias[lane];
        if (do_relu) v0 = fmaxf(v0, 0.f);
        hout[(size_t)node * F + lane] = v0;
        if (!BF && F == 128) {
            float v1 = acc1 * inv + bias[64 + lane];
            if (do_relu) v1 = fmaxf(v1, 0.f);
            hout[(size_t)node * F + 64 + lane] = v1;
        }
    }
}

__global__ void finalize_h(const float* __restrict__ h, float* __restrict__ outh,
                           const float* __restrict__ lpW, float* __restrict__ s1,
                           float* __restrict__ s2, int N) {
    int wave = (blockIdx.x * blockDim.x + threadIdx.x) >> 6;
    int lane = threadIdx.x & 63;
    if (wave >= N) return;
    float v = h[(size_t)wave * 64 + lane];
    outh[(size_t)wave * 64 + lane] = v;
    float a = v * lpW[lane];
    float b = v * lpW[64 + lane];
    for (int o = 32; o; o >>= 1) { a += __shfl_down(a, o); b += __shfl_down(b, o); }
    if (lane == 0) { s1[wave] = a; s2[wave] = b; }
}

// both edge lists in one launch
__global__ void scores2_k(const int* __restrict__ s, const int* __restrict__ d,
                          const int* __restrict__ ns, const int* __restrict__ nd,
                          const float* __restrict__ s1, const float* __restrict__ s2,
                          const float* __restrict__ lpb,
                          float* __restrict__ outp, float* __restrict__ outn, int E) {
    int i = blockIdx.x * blockDim.x + threadIdx.x;
    if (i < E) {
        outp[i] = s1[s[i]] + s2[d[i]] + lpb[0];
    } else if (i < 2 * E) {
        int j = i - E;
        outn[j] = s1[ns[j]] + s2[nd[j]] + lpb[0];
    }
}

// ---------------- driver ----------------

struct Scratch {
    float* feat; ushort_t* featbf; float* hA; float* hB;
    float* el; float* er; float* s1; float* s2;
    int* off; int* csrsrc; uint_t* gh; uint_t* bucketbase;
};

template <int K, int M, bool BF>
static void run_layer(const float* hin, const float* W, const float* al,
                      const float* ar, const float* b, bool relu,
                      float* hout, const Scratch& S, hipStream_t stream) {
    const int N = NN;
    constexpr int TPR = M / 4;
    int tthreads = (N / 4) * TPR;
    gemm_fused<K, M, BF><<<(tthreads + 255) / 256, 256, 0, stream>>>(
        hin, W, al, ar, S.feat, S.featbf, S.el, S.er, N);
    gat_agg<M, BF><<<(N + 3) / 4, 256, 0, stream>>>(S.off, S.csrsrc, S.el, S.er,
                                                    S.feat, S.featbf, b, hout, N, relu ? 1 : 0);
}

extern "C" void kernel_launch(void* const* d_in, const int* in_sizes, int n_in,
                              void* d_out, int out_size, void* d_ws, size_t ws_size,
                              hipStream_t stream) {
    const float* x   = (const float*)d_in[0];
    const float* W1  = (const float*)d_in[1];
    const float* al1 = (const float*)d_in[2];
    const float* ar1 = (const float*)d_in[3];
    const float* b1  = (const float*)d_in[4];
    const float* W2  = (const float*)d_in[5];
    const float* al2 = (const float*)d_in[6];
    const float* ar2 = (const float*)d_in[7];
    const float* b2  = (const float*)d_in[8];
    const float* W3  = (const float*)d_in[9];
    const float* al3 = (const float*)d_in[10];
    const float* ar3 = (const float*)d_in[11];
    const float* b3  = (const float*)d_in[12];
    const float* lpW = (const float*)d_in[13];
    const float* lpb = (const float*)d_in[14];
    const int* src  = (const int*)d_in[15];
    const int* dst  = (const int*)d_in[16];
    const int* nsrc = (const int*)d_in[17];
    const int* ndst = (const int*)d_in[18];

    char* w = (char*)d_ws;
    Scratch S;
    S.feat       = (float*)w;    w += (size_t)NN * 128 * 4;
    S.featbf     = (ushort_t*)w; w += (size_t)NN * 128 * 2;
    S.hA         = (float*)w;    w += (size_t)NN * 64 * 4;
    S.hB         = (float*)w;    w += (size_t)NN * 128 * 4;
    S.el         = (float*)w;    w += (size_t)NN * 4;
    S.er         = (float*)w;    w += (size_t)NN * 4;
    S.s1         = (float*)w;    w += (size_t)NN * 4;
    S.s2         = (float*)w;    w += (size_t)NN * 4;
    S.off        = (int*)w;      w += (size_t)(NN + 1) * 4;
    S.csrsrc     = (int*)w;      w += (size_t)NE * 4;
    S.gh         = (uint_t*)w;   w += (size_t)NT * NBKT * 4;
    S.bucketbase = (uint_t*)w;   w += (size_t)(NBKT + 1) * 4;

    // pairbuf aliases the fp32 feat buffer (CSR build completes before any layer runs;
    // fp32 feat is only used by layer 3)
    int2* pairbuf = (int2*)S.feat;

    // build dst-CSR once (bucketed counting sort); reused by all 3 layers
    part_hist<<<NT, 256, 0, stream>>>(dst, S.gh);
    scan_gh<<<1, 256, 0, stream>>>(S.gh, S.bucketbase);
    part_scatter<<<NT, 256, 0, stream>>>(src, dst, S.gh, pairbuf);
    bucket_csr<<<NBKT, 256, 0, stream>>>(pairbuf, S.bucketbase, S.off, S.csrsrc);

    // layer 1: x[50000,128] @ W1[128,64] -> hA, relu   (bf16 gather)
    run_layer<128, 64, true>(x, W1, al1, ar1, b1, true, S.hA, S, stream);
    // layer 2: hA[50000,64] @ W2[64,128] -> hB, relu   (bf16 gather)
    run_layer<64, 128, true>(S.hA, W2, al2, ar2, b2, true, S.hB, S, stream);
    // layer 3: hB[50000,128] @ W3[128,64] -> hA, no relu  (fp32 gather: output layer)
    run_layer<128, 64, false>(S.hB, W3, al3, ar3, b3, false, S.hA, S, stream);

    float* out_h   = (float*)d_out;
    float* out_pos = out_h + (size_t)NN * 64;
    float* out_neg = out_pos + NE;

    finalize_h<<<(NN + 3) / 4, 256, 0, stream>>>(S.hA, out_h, lpW, S.s1, S.s2, NN);
    scores2_k<<<(2 * NE + 255) / 256, 256, 0, stream>>>(src, dst, nsrc, ndst,
                                                        S.s1, S.s2, lpb, out_pos, out_neg, NE);
}

// Round 8
// 239.740 us; speedup vs baseline: 6.3429x; 1.1680x over previous
//
#include <hip/hip_runtime.h>
#include <hip/hip_bf16.h>

#define NN 50000
#define NE 800000
#define NBKT 196        // ceil(NN/256) buckets of 256 nodes
#define NT 200          // partition tiles
#define TILE 4000       // NE/NT exactly

typedef unsigned short ushort_t;
typedef unsigned int uint_t;

__device__ __forceinline__ float leaky(float v) { return (v >= 0.f) ? v : 0.2f * v; }
__device__ __forceinline__ ushort_t f2bf(float f) {
    __hip_bfloat16 h = __float2bfloat16(f);
    return *reinterpret_cast<ushort_t*>(&h);
}
__device__ __forceinline__ float bf_lo(uint_t v) { return __uint_as_float(v << 16); }
__device__ __forceinline__ float bf_hi(uint_t v) { return __uint_as_float(v & 0xFFFF0000u); }

// ---------------- CSR build: bucketed counting sort (no global atomics) ----------------

__global__ void part_hist(const int* __restrict__ dst, uint_t* __restrict__ gh) {
    __shared__ uint_t h[NBKT];
    int t = blockIdx.x, tid = threadIdx.x;
    for (int i = tid; i < NBKT; i += 256) h[i] = 0;
    __syncthreads();
    int e0 = t * TILE;
    for (int i = tid; i < TILE; i += 256)
        atomicAdd(&h[((uint_t)dst[e0 + i]) >> 8], 1u);
    __syncthreads();
    for (int i = tid; i < NBKT; i += 256) gh[t * NBKT + i] = h[i];
}

__global__ void scan_gh(uint_t* __restrict__ gh, uint_t* __restrict__ bucketbase) {
    int b = threadIdx.x;  // 256 threads
    uint_t run = 0;
    if (b < NBKT) {
        for (int t = 0; t < NT; ++t) {
            uint_t v = gh[t * NBKT + b];
            gh[t * NBKT + b] = run;
            run += v;
        }
    }
    int lane = b & 63, w = b >> 6;
    uint_t sc = run;
    for (int o = 1; o < 64; o <<= 1) {
        uint_t x = __shfl_up(sc, o);
        if (lane >= o) sc += x;
    }
    __shared__ uint_t ws4[4];
    if (lane == 63) ws4[w] = sc;
    __syncthreads();
    if (b == 0) { uint_t r = 0; for (int i = 0; i < 4; ++i) { uint_t tmp = ws4[i]; ws4[i] = r; r += tmp; } }
    __syncthreads();
    uint_t excl = ws4[w] + sc - run;
    if (b < NBKT) {
        bucketbase[b] = excl;
        for (int t = 0; t < NT; ++t) gh[t * NBKT + b] += excl;
    }
    if (b == NBKT - 1) bucketbase[NBKT] = excl + run;
}

__global__ void part_scatter(const int* __restrict__ src, const int* __restrict__ dst,
                             const uint_t* __restrict__ gh, int2* __restrict__ pairbuf) {
    __shared__ uint_t cur[NBKT];
    int t = blockIdx.x, tid = threadIdx.x;
    for (int i = tid; i < NBKT; i += 256) cur[i] = gh[t * NBKT + i];
    __syncthreads();
    int e0 = t * TILE;
    for (int i = tid; i < TILE; i += 256) {
        int d = dst[e0 + i], s = src[e0 + i];
        uint_t pos = atomicAdd(&cur[((uint_t)d) >> 8], 1u);
        pairbuf[pos] = make_int2(s, d);
    }
}

__global__ void bucket_csr(const int2* __restrict__ pairbuf, const uint_t* __restrict__ bucketbase,
                           int* __restrict__ off, int* __restrict__ csrsrc) {
    int b = blockIdx.x, tid = threadIdx.x;
    uint_t eb0 = bucketbase[b], m = bucketbase[b + 1] - eb0;
    __shared__ uint_t cnt[256];
    __shared__ uint_t ws4[4];
    cnt[tid] = 0;
    __syncthreads();
    for (uint_t i = tid; i < m; i += 256)
        atomicAdd(&cnt[pairbuf[eb0 + i].y & 255], 1u);
    __syncthreads();
    uint_t v = cnt[tid];
    int lane = tid & 63, w = tid >> 6;
    uint_t sc = v;
    for (int o = 1; o < 64; o <<= 1) {
        uint_t x = __shfl_up(sc, o);
        if (lane >= o) sc += x;
    }
    if (lane == 63) ws4[w] = sc;
    __syncthreads();
    if (tid == 0) { uint_t r = 0; for (int i = 0; i < 4; ++i) { uint_t tmp = ws4[i]; ws4[i] = r; r += tmp; } }
    __syncthreads();
    uint_t excl = ws4[w] + sc - v;
    int node = b * 256 + tid;
    if (node < NN) off[node] = (int)(eb0 + excl);
    if (b == 0 && tid == 0) off[NN] = NE;
    __syncthreads();
    cnt[tid] = eb0 + excl;  // reuse as cursor
    __syncthreads();
    for (uint_t i = tid; i < m; i += 256) {
        int2 p = pairbuf[eb0 + i];
        uint_t pos = atomicAdd(&cnt[p.y & 255], 1u);
        csrsrc[pos] = p.x;
    }
}

// ---------------- per-layer kernels ----------------

#define FMA4(a, s, b) { (a).x += (s) * (b).x; (a).y += (s) * (b).y; (a).z += (s) * (b).z; (a).w += (s) * (b).w; }
__device__ __forceinline__ float dot4(float4 a, float4 b) {
    return a.x * b.x + a.y * b.y + a.z * b.z + a.w * b.w;
}

// 4 nodes x 4 m-cols per thread; fused el/er epilogue; feat stored packed bf16
template <int K, int M>
__global__ void gemm_fused(const float* __restrict__ X, const float* __restrict__ W,
                           const float* __restrict__ al, const float* __restrict__ ar,
                           ushort_t* __restrict__ featbf,
                           float* __restrict__ el, float* __restrict__ er, int N) {
    constexpr int TPR = M / 4;
    int idx = blockIdx.x * blockDim.x + threadIdx.x;
    int ng = idx / TPR;
    int tmi = idx % TPR;
    int tm = tmi * 4;
    int n0 = ng * 4;
    if (n0 >= N) return;
    const float* x0 = X + (size_t)n0 * K;

    float4 acc[4];
    #pragma unroll
    for (int j = 0; j < 4; ++j) acc[j] = make_float4(0.f, 0.f, 0.f, 0.f);

    for (int k0 = 0; k0 < K; k0 += 4) {
        float4 xv[4], wv[4];
        #pragma unroll
        for (int j = 0; j < 4; ++j)
            xv[j] = *reinterpret_cast<const float4*>(x0 + (size_t)j * K + k0);
        #pragma unroll
        for (int kk = 0; kk < 4; ++kk)
            wv[kk] = *reinterpret_cast<const float4*>(W + (size_t)(k0 + kk) * M + tm);
        #pragma unroll
        for (int j = 0; j < 4; ++j) {
            FMA4(acc[j], xv[j].x, wv[0]);
            FMA4(acc[j], xv[j].y, wv[1]);
            FMA4(acc[j], xv[j].z, wv[2]);
            FMA4(acc[j], xv[j].w, wv[3]);
        }
    }

    #pragma unroll
    for (int j = 0; j < 4; ++j) {
        uint2 pr;
        pr.x = ((uint_t)f2bf(acc[j].y) << 16) | (uint_t)f2bf(acc[j].x);
        pr.y = ((uint_t)f2bf(acc[j].w) << 16) | (uint_t)f2bf(acc[j].z);
        *reinterpret_cast<uint2*>(featbf + (size_t)(n0 + j) * M + tm) = pr;
    }

    float4 a4 = *reinterpret_cast<const float4*>(&al[tm]);
    float4 r4 = *reinterpret_cast<const float4*>(&ar[tm]);
    float elp[4], erp[4];
    #pragma unroll
    for (int j = 0; j < 4; ++j) { elp[j] = dot4(acc[j], a4); erp[j] = dot4(acc[j], r4); }
    #pragma unroll
    for (int o = 1; o < TPR; o <<= 1) {
        #pragma unroll
        for (int j = 0; j < 4; ++j) {
            elp[j] += __shfl_xor(elp[j], o);
            erp[j] += __shfl_xor(erp[j], o);
        }
    }
    if (tmi == 0) {
        #pragma unroll
        for (int j = 0; j < 4; ++j) { el[n0 + j] = elp[j]; er[n0 + j] = erp[j]; }
    }
}

// 32 lanes per node (2 nodes/wave): edge-softmax + bf16 weighted gather.
// FIN: also compute link-pred partials s1/s2 (F==64 only).
template <int F, bool FIN>
__global__ void gat_agg2(const int* __restrict__ off, const int* __restrict__ csrsrc,
                         const float* __restrict__ el, const float* __restrict__ er,
                         const ushort_t* __restrict__ featbf, const float* __restrict__ bias,
                         float* __restrict__ hout, const float* __restrict__ lpW,
                         float* __restrict__ s1, float* __restrict__ s2,
                         int N, int do_relu) {
    int g = blockIdx.x * blockDim.x + threadIdx.x;
    int node = g >> 5;
    int sub = threadIdx.x & 31;
    if (node >= N) return;
    int start = off[node], deg = off[node + 1] - start;
    float ern = er[node];

    int s0 = 0; float e0 = -1e30f;
    if (sub < deg) { s0 = csrsrc[start + sub]; e0 = leaky(el[s0] + ern); }
    float m = e0;
    for (int i = 32 + sub; i < deg; i += 32)
        m = fmaxf(m, leaky(el[csrsrc[start + i]] + ern));
    for (int o = 16; o; o >>= 1) m = fmaxf(m, __shfl_xor(m, o));

    float p0 = (sub < deg) ? __expf(e0 - m) : 0.f;
    float ssum = p0;
    for (int i = 32 + sub; i < deg; i += 32)
        ssum += __expf(leaky(el[csrsrc[start + i]] + ern) - m);
    for (int o = 16; o; o >>= 1) ssum += __shfl_xor(ssum, o);
    float inv = (deg > 0) ? 1.f / ssum : 0.f;

    float acc0 = 0.f, acc1 = 0.f, acc2 = 0.f, acc3 = 0.f;
    int head = (deg < 32) ? deg : 32;
    int i = 0;
    for (; i + 4 <= head; i += 4) {
        float pA = __shfl(p0, i, 32), pB = __shfl(p0, i + 1, 32),
              pC = __shfl(p0, i + 2, 32), pD = __shfl(p0, i + 3, 32);
        int sA = __shfl(s0, i, 32), sB = __shfl(s0, i + 1, 32),
            sC = __shfl(s0, i + 2, 32), sD = __shfl(s0, i + 3, 32);
        if (F == 128) {
            uint2 vA = ((const uint2*)(featbf + (size_t)sA * F))[sub];
            uint2 vB = ((const uint2*)(featbf + (size_t)sB * F))[sub];
            uint2 vC = ((const uint2*)(featbf + (size_t)sC * F))[sub];
            uint2 vD = ((const uint2*)(featbf + (size_t)sD * F))[sub];
            acc0 += pA * bf_lo(vA.x) + pB * bf_lo(vB.x) + pC * bf_lo(vC.x) + pD * bf_lo(vD.x);
            acc1 += pA * bf_hi(vA.x) + pB * bf_hi(vB.x) + pC * bf_hi(vC.x) + pD * bf_hi(vD.x);
            acc2 += pA * bf_lo(vA.y) + pB * bf_lo(vB.y) + pC * bf_lo(vC.y) + pD * bf_lo(vD.y);
            acc3 += pA * bf_hi(vA.y) + pB * bf_hi(vB.y) + pC * bf_hi(vC.y) + pD * bf_hi(vD.y);
        } else {
            uint_t vA = ((const uint_t*)(featbf + (size_t)sA * F))[sub];
            uint_t vB = ((const uint_t*)(featbf + (size_t)sB * F))[sub];
            uint_t vC = ((const uint_t*)(featbf + (size_t)sC * F))[sub];
            uint_t vD = ((const uint_t*)(featbf + (size_t)sD * F))[sub];
            acc0 += pA * bf_lo(vA) + pB * bf_lo(vB) + pC * bf_lo(vC) + pD * bf_lo(vD);
            acc1 += pA * bf_hi(vA) + pB * bf_hi(vB) + pC * bf_hi(vC) + pD * bf_hi(vD);
        }
    }
    for (; i < head; ++i) {
        float p = __shfl(p0, i, 32);
        int sN = __shfl(s0, i, 32);
        if (F == 128) {
            uint2 v = ((const uint2*)(featbf + (size_t)sN * F))[sub];
            acc0 += p * bf_lo(v.x); acc1 += p * bf_hi(v.x);
            acc2 += p * bf_lo(v.y); acc3 += p * bf_hi(v.y);
        } else {
            uint_t v = ((const uint_t*)(featbf + (size_t)sN * F))[sub];
            acc0 += p * bf_lo(v); acc1 += p * bf_hi(v);
        }
    }
    for (i = 32; i < deg; ++i) {  // rare tail (deg>32): recompute p (broadcast)
        int sN = csrsrc[start + i];
        float p = __expf(leaky(el[sN] + ern) - m);
        if (F == 128) {
            uint2 v = ((const uint2*)(featbf + (size_t)sN * F))[sub];
            acc0 += p * bf_lo(v.x); acc1 += p * bf_hi(v.x);
            acc2 += p * bf_lo(v.y); acc3 += p * bf_hi(v.y);
        } else {
            uint_t v = ((const uint_t*)(featbf + (size_t)sN * F))[sub];
            acc0 += p * bf_lo(v); acc1 += p * bf_hi(v);
        }
    }

    if (F == 128) {
        float4 b4 = ((const float4*)bias)[sub];
        float v0 = acc0 * inv + b4.x, v1 = acc1 * inv + b4.y;
        float v2 = acc2 * inv + b4.z, v3 = acc3 * inv + b4.w;
        if (do_relu) {
            v0 = fmaxf(v0, 0.f); v1 = fmaxf(v1, 0.f);
            v2 = fmaxf(v2, 0.f); v3 = fmaxf(v3, 0.f);
        }
        ((float4*)(hout + (size_t)node * 128))[sub] = make_float4(v0, v1, v2, v3);
    } else {
        float2 b2 = ((const float2*)bias)[sub];
        float v0 = acc0 * inv + b2.x, v1 = acc1 * inv + b2.y;
        if (do_relu) { v0 = fmaxf(v0, 0.f); v1 = fmaxf(v1, 0.f); }
        ((float2*)(hout + (size_t)node * 64))[sub] = make_float2(v0, v1);
        if (FIN) {
            float2 wl = ((const float2*)lpW)[sub];
            float2 wr = ((const float2*)(lpW + 64))[sub];
            float a = v0 * wl.x + v1 * wl.y;
            float b = v0 * wr.x + v1 * wr.y;
            for (int o = 16; o; o >>= 1) { a += __shfl_xor(a, o); b += __shfl_xor(b, o); }
            if (sub == 0) { s1[node] = a; s2[node] = b; }
        }
    }
}

// both edge lists in one launch
__global__ void scores2_k(const int* __restrict__ s, const int* __restrict__ d,
                          const int* __restrict__ ns, const int* __restrict__ nd,
                          const float* __restrict__ s1, const float* __restrict__ s2,
                          const float* __restrict__ lpb,
                          float* __restrict__ outp, float* __restrict__ outn, int E) {
    int i = blockIdx.x * blockDim.x + threadIdx.x;
    if (i < E) {
        outp[i] = s1[s[i]] + s2[d[i]] + lpb[0];
    } else if (i < 2 * E) {
        int j = i - E;
        outn[j] = s1[ns[j]] + s2[nd[j]] + lpb[0];
    }
}

// ---------------- driver ----------------

struct Scratch {
    float* feat; ushort_t* featbf; float* hA; float* hB;
    float* el; float* er; float* s1; float* s2;
    int* off; int* csrsrc; uint_t* gh; uint_t* bucketbase;
};

template <int K, int M, bool FIN>
static void run_layer(const float* hin, const float* W, const float* al,
                      const float* ar, const float* b, bool relu,
                      float* hout, const float* lpW, const Scratch& S, hipStream_t stream) {
    const int N = NN;
    constexpr int TPR = M / 4;
    int tthreads = (N / 4) * TPR;
    gemm_fused<K, M><<<(tthreads + 255) / 256, 256, 0, stream>>>(
        hin, W, al, ar, S.featbf, S.el, S.er, N);
    gat_agg2<M, FIN><<<(N * 32 + 255) / 256, 256, 0, stream>>>(
        S.off, S.csrsrc, S.el, S.er, S.featbf, b, hout, lpW, S.s1, S.s2, N, relu ? 1 : 0);
}

extern "C" void kernel_launch(void* const* d_in, const int* in_sizes, int n_in,
                              void* d_out, int out_size, void* d_ws, size_t ws_size,
                              hipStream_t stream) {
    const float* x   = (const float*)d_in[0];
    const float* W1  = (const float*)d_in[1];
    const float* al1 = (const float*)d_in[2];
    const float* ar1 = (const float*)d_in[3];
    const float* b1  = (const float*)d_in[4];
    const float* W2  = (const float*)d_in[5];
    const float* al2 = (const float*)d_in[6];
    const float* ar2 = (const float*)d_in[7];
    const float* b2  = (const float*)d_in[8];
    const float* W3  = (const float*)d_in[9];
    const float* al3 = (const float*)d_in[10];
    const float* ar3 = (const float*)d_in[11];
    const float* b3  = (const float*)d_in[12];
    const float* lpW = (const float*)d_in[13];
    const float* lpb = (const float*)d_in[14];
    const int* src  = (const int*)d_in[15];
    const int* dst  = (const int*)d_in[16];
    const int* nsrc = (const int*)d_in[17];
    const int* ndst = (const int*)d_in[18];

    char* w = (char*)d_ws;
    Scratch S;
    S.feat       = (float*)w;    w += (size_t)NN * 128 * 4;   // used only as pairbuf alias
    S.featbf     = (ushort_t*)w; w += (size_t)NN * 128 * 2;
    S.hA         = (float*)w;    w += (size_t)NN * 64 * 4;
    S.hB         = (float*)w;    w += (size_t)NN * 128 * 4;
    S.el         = (float*)w;    w += (size_t)NN * 4;
    S.er         = (float*)w;    w += (size_t)NN * 4;
    S.s1         = (float*)w;    w += (size_t)NN * 4;
    S.s2         = (float*)w;    w += (size_t)NN * 4;
    S.off        = (int*)w;      w += (size_t)(NN + 1) * 4;
    S.csrsrc     = (int*)w;      w += (size_t)NE * 4;
    S.gh         = (uint_t*)w;   w += (size_t)NT * NBKT * 4;
    S.bucketbase = (uint_t*)w;   w += (size_t)(NBKT + 1) * 4;

    // pairbuf aliases the fp32 feat buffer (CSR build completes before any layer runs)
    int2* pairbuf = (int2*)S.feat;

    // build dst-CSR once (bucketed counting sort); reused by all 3 layers
    part_hist<<<NT, 256, 0, stream>>>(dst, S.gh);
    scan_gh<<<1, 256, 0, stream>>>(S.gh, S.bucketbase);
    part_scatter<<<NT, 256, 0, stream>>>(src, dst, S.gh, pairbuf);
    bucket_csr<<<NBKT, 256, 0, stream>>>(pairbuf, S.bucketbase, S.off, S.csrsrc);

    float* out_h   = (float*)d_out;
    float* out_pos = out_h + (size_t)NN * 64;
    float* out_neg = out_pos + NE;

    // layer 1: x[50000,128] @ W1[128,64] -> hA, relu
    run_layer<128, 64, false>(x, W1, al1, ar1, b1, true, S.hA, nullptr, S, stream);
    // layer 2: hA[50000,64] @ W2[64,128] -> hB, relu
    run_layer<64, 128, false>(S.hA, W2, al2, ar2, b2, true, S.hB, nullptr, S, stream);
    // layer 3: hB[50000,128] @ W3[128,64] -> d_out h directly, + fused link-pred partials
    run_layer<128, 64, true>(S.hB, W3, al3, ar3, b3, false, out_h, lpW, S, stream);

    scores2_k<<<(2 * NE + 255) / 256, 256, 0, stream>>>(src, dst, nsrc, ndst,
                                                        S.s1, S.s2, lpb, out_pos, out_neg, NE);
}

// Round 9
// 222.770 us; speedup vs baseline: 6.8261x; 1.0762x over previous
//
#include <hip/hip_runtime.h>
#include <hip/hip_bf16.h>

#define NN 50000
#define NE 800000
#define NBKT 196        // ceil(NN/256) buckets of 256 nodes
#define NT 200          // partition tiles
#define TILE 4000       // NE/NT exactly

typedef unsigned short ushort_t;
typedef unsigned int uint_t;

typedef __bf16 bf16_t;
typedef bf16_t bf16x8 __attribute__((ext_vector_type(8)));
typedef float f32x4 __attribute__((ext_vector_type(4)));

__device__ __forceinline__ float leaky(float v) { return (v >= 0.f) ? v : 0.2f * v; }
__device__ __forceinline__ ushort_t f2bf(float f) {
    __hip_bfloat16 h = __float2bfloat16(f);
    return *reinterpret_cast<ushort_t*>(&h);
}
__device__ __forceinline__ float bf_lo(uint_t v) { return __uint_as_float(v << 16); }
__device__ __forceinline__ float bf_hi(uint_t v) { return __uint_as_float(v & 0xFFFF0000u); }

// ---------------- prep: fp32 -> bf16 conversions ----------------

// x [N*128] fp32 -> bf16 (8 elems/thread)
__global__ void conv_x(const float* __restrict__ X, ushort_t* __restrict__ Xbf, int total8) {
    int i = blockIdx.x * blockDim.x + threadIdx.x;
    if (i >= total8) return;
    const float4* p = reinterpret_cast<const float4*>(X + (size_t)i * 8);
    float4 a = p[0], b = p[1];
    uint4 o;
    o.x = ((uint_t)f2bf(a.y) << 16) | f2bf(a.x);
    o.y = ((uint_t)f2bf(a.w) << 16) | f2bf(a.z);
    o.z = ((uint_t)f2bf(b.y) << 16) | f2bf(b.x);
    o.w = ((uint_t)f2bf(b.w) << 16) | f2bf(b.z);
    *reinterpret_cast<uint4*>(Xbf + (size_t)i * 8) = o;
}

// transpose + bf16 the three weight matrices (tiny)
__global__ void prep_w(const float* __restrict__ W1, const float* __restrict__ W2,
                       const float* __restrict__ W3, ushort_t* __restrict__ Wt1,
                       ushort_t* __restrict__ Wt2, ushort_t* __restrict__ Wt3) {
    int tid = threadIdx.x;  // 256
    for (int i = tid; i < 128 * 64; i += 256) { int k = i >> 6, m = i & 63; Wt1[m * 128 + k] = f2bf(W1[i]); }
    for (int i = tid; i < 64 * 128; i += 256) { int k = i >> 7, m = i & 127; Wt2[m * 64 + k] = f2bf(W2[i]); }
    for (int i = tid; i < 128 * 64; i += 256) { int k = i >> 6, m = i & 63; Wt3[m * 128 + k] = f2bf(W3[i]); }
}

// ---------------- CSR build: bucketed counting sort ----------------

__global__ void part_hist(const int* __restrict__ dst, uint_t* __restrict__ gh) {
    __shared__ uint_t h[NBKT];
    int t = blockIdx.x, tid = threadIdx.x;
    for (int i = tid; i < NBKT; i += 256) h[i] = 0;
    __syncthreads();
    int e0 = t * TILE;
    for (int i = tid; i < TILE; i += 256)
        atomicAdd(&h[((uint_t)dst[e0 + i]) >> 8], 1u);
    __syncthreads();
    for (int i = tid; i < NBKT; i += 256) gh[t * NBKT + i] = h[i];
}

__global__ void scan_gh(uint_t* __restrict__ gh, uint_t* __restrict__ bucketbase) {
    int b = threadIdx.x;  // 256 threads
    uint_t run = 0;
    if (b < NBKT) {
        for (int t = 0; t < NT; ++t) {
            uint_t v = gh[t * NBKT + b];
            gh[t * NBKT + b] = run;
            run += v;
        }
    }
    int lane = b & 63, w = b >> 6;
    uint_t sc = run;
    for (int o = 1; o < 64; o <<= 1) {
        uint_t x = __shfl_up(sc, o);
        if (lane >= o) sc += x;
    }
    __shared__ uint_t ws4[4];
    if (lane == 63) ws4[w] = sc;
    __syncthreads();
    if (b == 0) { uint_t r = 0; for (int i = 0; i < 4; ++i) { uint_t tmp = ws4[i]; ws4[i] = r; r += tmp; } }
    __syncthreads();
    uint_t excl = ws4[w] + sc - run;
    if (b < NBKT) {
        bucketbase[b] = excl;
        for (int t = 0; t < NT; ++t) gh[t * NBKT + b] += excl;
    }
    if (b == NBKT - 1) bucketbase[NBKT] = excl + run;
}

__global__ void part_scatter(const int* __restrict__ src, const int* __restrict__ dst,
                             const uint_t* __restrict__ gh, int2* __restrict__ pairbuf) {
    __shared__ uint_t cur[NBKT];
    int t = blockIdx.x, tid = threadIdx.x;
    for (int i = tid; i < NBKT; i += 256) cur[i] = gh[t * NBKT + i];
    __syncthreads();
    int e0 = t * TILE;
    for (int i = tid; i < TILE; i += 256) {
        int d = dst[e0 + i], s = src[e0 + i];
        uint_t pos = atomicAdd(&cur[((uint_t)d) >> 8], 1u);
        pairbuf[pos] = make_int2(s, d);
    }
}

__global__ void bucket_csr(const int2* __restrict__ pairbuf, const uint_t* __restrict__ bucketbase,
                           int* __restrict__ off, int* __restrict__ csrsrc) {
    int b = blockIdx.x, tid = threadIdx.x;
    uint_t eb0 = bucketbase[b], m = bucketbase[b + 1] - eb0;
    __shared__ uint_t cnt[256];
    __shared__ uint_t ws4[4];
    cnt[tid] = 0;
    __syncthreads();
    for (uint_t i = tid; i < m; i += 256)
        atomicAdd(&cnt[pairbuf[eb0 + i].y & 255], 1u);
    __syncthreads();
    uint_t v = cnt[tid];
    int lane = tid & 63, w = tid >> 6;
    uint_t sc = v;
    for (int o = 1; o < 64; o <<= 1) {
        uint_t x = __shfl_up(sc, o);
        if (lane >= o) sc += x;
    }
    if (lane == 63) ws4[w] = sc;
    __syncthreads();
    if (tid == 0) { uint_t r = 0; for (int i = 0; i < 4; ++i) { uint_t tmp = ws4[i]; ws4[i] = r; r += tmp; } }
    __syncthreads();
    uint_t excl = ws4[w] + sc - v;
    int node = b * 256 + tid;
    if (node < NN) off[node] = (int)(eb0 + excl);
    if (b == 0 && tid == 0) off[NN] = NE;
    __syncthreads();
    cnt[tid] = eb0 + excl;  // reuse as cursor
    __syncthreads();
    for (uint_t i = tid; i < m; i += 256) {
        int2 p = pairbuf[eb0 + i];
        uint_t pos = atomicAdd(&cnt[p.y & 255], 1u);
        csrsrc[pos] = p.x;
    }
}

// ---------------- MFMA GEMM: feat = Xbf @ W (Wt is [M][K] bf16), fused el/er ----------------
// block = 256 thr (4 waves), 16 nodes per block; wave handles CT=M/64 16x16 col tiles.
// A/B frag: lane holds 8 contiguous k at (lane&15 row/col, (lane>>4)*8 k-offset).
// C frag (m89-verified): col = lane&15, row = (lane>>4)*4 + j.
template <int K, int M>
__global__ void gemm_mfma(const ushort_t* __restrict__ Xbf, const ushort_t* __restrict__ Wt,
                          const float* __restrict__ al, const float* __restrict__ ar,
                          ushort_t* __restrict__ featbf, float* __restrict__ el,
                          float* __restrict__ er, int N) {
    constexpr int CT = M / 64;   // col tiles per wave
    constexpr int KI = K / 32;   // k steps
    int wv = threadIdx.x >> 6, lane = threadIdx.x & 63;
    int c = lane & 15, kq = lane >> 4;
    int n0 = blockIdx.x * 16;

    const ushort_t* aptr = Xbf + (size_t)(n0 + c) * K + kq * 8;

    f32x4 acc[CT];
    #pragma unroll
    for (int ct = 0; ct < CT; ++ct) acc[ct] = (f32x4){0.f, 0.f, 0.f, 0.f};

    #pragma unroll
    for (int ki = 0; ki < KI; ++ki) {
        bf16x8 a = *reinterpret_cast<const bf16x8*>(aptr + ki * 32);
        #pragma unroll
        for (int ct = 0; ct < CT; ++ct) {
            int colb = (wv * CT + ct) * 16;
            bf16x8 b = *reinterpret_cast<const bf16x8*>(
                Wt + (size_t)(colb + c) * K + kq * 8 + ki * 32);
            acc[ct] = __builtin_amdgcn_mfma_f32_16x16x32_bf16(a, b, acc[ct], 0, 0, 0);
        }
    }

    // epilogue: store bf16 feat + fused el/er (fp32)
    float pe[4] = {0.f, 0.f, 0.f, 0.f}, pr[4] = {0.f, 0.f, 0.f, 0.f};
    #pragma unroll
    for (int ct = 0; ct < CT; ++ct) {
        int colb = (wv * CT + ct) * 16;
        float alv = al[colb + c], arv = ar[colb + c];
        #pragma unroll
        for (int j = 0; j < 4; ++j) {
            float v = acc[ct][j];
            featbf[(size_t)(n0 + kq * 4 + j) * M + colb + c] = f2bf(v);
            pe[j] += v * alv;
            pr[j] += v * arv;
        }
    }
    #pragma unroll
    for (int o = 1; o < 16; o <<= 1) {
        #pragma unroll
        for (int j = 0; j < 4; ++j) {
            pe[j] += __shfl_xor(pe[j], o);
            pr[j] += __shfl_xor(pr[j], o);
        }
    }
    __shared__ float els[4][16], ers[4][16];
    if (c == 0) {
        #pragma unroll
        for (int j = 0; j < 4; ++j) { els[wv][kq * 4 + j] = pe[j]; ers[wv][kq * 4 + j] = pr[j]; }
    }
    __syncthreads();
    if (threadIdx.x < 16) {
        int t = threadIdx.x;
        el[n0 + t] = els[0][t] + els[1][t] + els[2][t] + els[3][t];
        er[n0 + t] = ers[0][t] + ers[1][t] + ers[2][t] + ers[3][t];
    }
}

// ---------------- aggregation: 32 lanes per node ----------------
// BFOUT: write h as packed bf16 (layers 1-2). FIN: fp32 h + link-pred partials (layer 3).
template <int F, bool FIN, bool BFOUT>
__global__ void gat_agg2(const int* __restrict__ off, const int* __restrict__ csrsrc,
                         const float* __restrict__ el, const float* __restrict__ er,
                         const ushort_t* __restrict__ featbf, const float* __restrict__ bias,
                         void* __restrict__ hout, const float* __restrict__ lpW,
                         float* __restrict__ s1, float* __restrict__ s2,
                         int N, int do_relu) {
    int g = blockIdx.x * blockDim.x + threadIdx.x;
    int node = g >> 5;
    int sub = threadIdx.x & 31;
    if (node >= N) return;
    int start = off[node], deg = off[node + 1] - start;
    float ern = er[node];

    int s0 = 0; float e0 = -1e30f;
    if (sub < deg) { s0 = csrsrc[start + sub]; e0 = leaky(el[s0] + ern); }
    float m = e0;
    for (int i = 32 + sub; i < deg; i += 32)
        m = fmaxf(m, leaky(el[csrsrc[start + i]] + ern));
    for (int o = 16; o; o >>= 1) m = fmaxf(m, __shfl_xor(m, o));

    float p0 = (sub < deg) ? __expf(e0 - m) : 0.f;
    float ssum = p0;
    for (int i = 32 + sub; i < deg; i += 32)
        ssum += __expf(leaky(el[csrsrc[start + i]] + ern) - m);
    for (int o = 16; o; o >>= 1) ssum += __shfl_xor(ssum, o);
    float inv = (deg > 0) ? 1.f / ssum : 0.f;

    float acc0 = 0.f, acc1 = 0.f, acc2 = 0.f, acc3 = 0.f;
    int head = (deg < 32) ? deg : 32;
    int i = 0;
    for (; i + 4 <= head; i += 4) {
        float pA = __shfl(p0, i, 32), pB = __shfl(p0, i + 1, 32),
              pC = __shfl(p0, i + 2, 32), pD = __shfl(p0, i + 3, 32);
        int sA = __shfl(s0, i, 32), sB = __shfl(s0, i + 1, 32),
            sC = __shfl(s0, i + 2, 32), sD = __shfl(s0, i + 3, 32);
        if (F == 128) {
            uint2 vA = ((const uint2*)(featbf + (size_t)sA * F))[sub];
            uint2 vB = ((const uint2*)(featbf + (size_t)sB * F))[sub];
            uint2 vC = ((const uint2*)(featbf + (size_t)sC * F))[sub];
            uint2 vD = ((const uint2*)(featbf + (size_t)sD * F))[sub];
            acc0 += pA * bf_lo(vA.x) + pB * bf_lo(vB.x) + pC * bf_lo(vC.x) + pD * bf_lo(vD.x);
            acc1 += pA * bf_hi(vA.x) + pB * bf_hi(vB.x) + pC * bf_hi(vC.x) + pD * bf_hi(vD.x);
            acc2 += pA * bf_lo(vA.y) + pB * bf_lo(vB.y) + pC * bf_lo(vC.y) + pD * bf_lo(vD.y);
            acc3 += pA * bf_hi(vA.y) + pB * bf_hi(vB.y) + pC * bf_hi(vC.y) + pD * bf_hi(vD.y);
        } else {
            uint_t vA = ((const uint_t*)(featbf + (size_t)sA * F))[sub];
            uint_t vB = ((const uint_t*)(featbf + (size_t)sB * F))[sub];
            uint_t vC = ((const uint_t*)(featbf + (size_t)sC * F))[sub];
            uint_t vD = ((const uint_t*)(featbf + (size_t)sD * F))[sub];
            acc0 += pA * bf_lo(vA) + pB * bf_lo(vB) + pC * bf_lo(vC) + pD * bf_lo(vD);
            acc1 += pA * bf_hi(vA) + pB * bf_hi(vB) + pC * bf_hi(vC) + pD * bf_hi(vD);
        }
    }
    for (; i < head; ++i) {
        float p = __shfl(p0, i, 32);
        int sN = __shfl(s0, i, 32);
        if (F == 128) {
            uint2 v = ((const uint2*)(featbf + (size_t)sN * F))[sub];
            acc0 += p * bf_lo(v.x); acc1 += p * bf_hi(v.x);
            acc2 += p * bf_lo(v.y); acc3 += p * bf_hi(v.y);
        } else {
            uint_t v = ((const uint_t*)(featbf + (size_t)sN * F))[sub];
            acc0 += p * bf_lo(v); acc1 += p * bf_hi(v);
        }
    }
    for (i = 32; i < deg; ++i) {  // rare tail (deg>32)
        int sN = csrsrc[start + i];
        float p = __expf(leaky(el[sN] + ern) - m);
        if (F == 128) {
            uint2 v = ((const uint2*)(featbf + (size_t)sN * F))[sub];
            acc0 += p * bf_lo(v.x); acc1 += p * bf_hi(v.x);
            acc2 += p * bf_lo(v.y); acc3 += p * bf_hi(v.y);
        } else {
            uint_t v = ((const uint_t*)(featbf + (size_t)sN * F))[sub];
            acc0 += p * bf_lo(v); acc1 += p * bf_hi(v);
        }
    }

    if (F == 128) {
        float4 b4 = ((const float4*)bias)[sub];
        float v0 = acc0 * inv + b4.x, v1 = acc1 * inv + b4.y;
        float v2 = acc2 * inv + b4.z, v3 = acc3 * inv + b4.w;
        if (do_relu) {
            v0 = fmaxf(v0, 0.f); v1 = fmaxf(v1, 0.f);
            v2 = fmaxf(v2, 0.f); v3 = fmaxf(v3, 0.f);
        }
        if (BFOUT) {
            uint2 pr;
            pr.x = ((uint_t)f2bf(v1) << 16) | f2bf(v0);
            pr.y = ((uint_t)f2bf(v3) << 16) | f2bf(v2);
            ((uint2*)hout)[(size_t)node * 32 + sub] = pr;
        } else {
            ((float4*)hout)[(size_t)node * 32 + sub] = make_float4(v0, v1, v2, v3);
        }
    } else {
        float2 b2 = ((const float2*)bias)[sub];
        float v0 = acc0 * inv + b2.x, v1 = acc1 * inv + b2.y;
        if (do_relu) { v0 = fmaxf(v0, 0.f); v1 = fmaxf(v1, 0.f); }
        if (BFOUT) {
            ((uint_t*)hout)[(size_t)node * 32 + sub] = ((uint_t)f2bf(v1) << 16) | f2bf(v0);
        } else {
            ((float2*)hout)[(size_t)node * 32 + sub] = make_float2(v0, v1);
        }
        if (FIN) {
            float2 wl = ((const float2*)lpW)[sub];
            float2 wr = ((const float2*)(lpW + 64))[sub];
            float a = v0 * wl.x + v1 * wl.y;
            float b = v0 * wr.x + v1 * wr.y;
            for (int o = 16; o; o >>= 1) { a += __shfl_xor(a, o); b += __shfl_xor(b, o); }
            if (sub == 0) { s1[node] = a; s2[node] = b; }
        }
    }
}

// both edge lists in one launch
__global__ void scores2_k(const int* __restrict__ s, const int* __restrict__ d,
                          const int* __restrict__ ns, const int* __restrict__ nd,
                          const float* __restrict__ s1, const float* __restrict__ s2,
                          const float* __restrict__ lpb,
                          float* __restrict__ outp, float* __restrict__ outn, int E) {
    int i = blockIdx.x * blockDim.x + threadIdx.x;
    if (i < E) {
        outp[i] = s1[s[i]] + s2[d[i]] + lpb[0];
    } else if (i < 2 * E) {
        int j = i - E;
        outn[j] = s1[ns[j]] + s2[nd[j]] + lpb[0];
    }
}

// ---------------- driver ----------------

struct Scratch {
    ushort_t* xbf; ushort_t* wt1; ushort_t* wt2; ushort_t* wt3;
    ushort_t* featbf; ushort_t* hAbf; ushort_t* hBbf;
    float* el; float* er; float* s1; float* s2;
    int* off; int* csrsrc; uint_t* gh; uint_t* bucketbase;
    int2* pairbuf;
};

extern "C" void kernel_launch(void* const* d_in, const int* in_sizes, int n_in,
                              void* d_out, int out_size, void* d_ws, size_t ws_size,
                              hipStream_t stream) {
    const float* x   = (const float*)d_in[0];
    const float* W1  = (const float*)d_in[1];
    const float* al1 = (const float*)d_in[2];
    const float* ar1 = (const float*)d_in[3];
    const float* b1  = (const float*)d_in[4];
    const float* W2  = (const float*)d_in[5];
    const float* al2 = (const float*)d_in[6];
    const float* ar2 = (const float*)d_in[7];
    const float* b2  = (const float*)d_in[8];
    const float* W3  = (const float*)d_in[9];
    const float* al3 = (const float*)d_in[10];
    const float* ar3 = (const float*)d_in[11];
    const float* b3  = (const float*)d_in[12];
    const float* lpW = (const float*)d_in[13];
    const float* lpb = (const float*)d_in[14];
    const int* src  = (const int*)d_in[15];
    const int* dst  = (const int*)d_in[16];
    const int* nsrc = (const int*)d_in[17];
    const int* ndst = (const int*)d_in[18];

    char* w = (char*)d_ws;
    Scratch S;
    S.xbf        = (ushort_t*)w; w += (size_t)NN * 128 * 2;
    S.featbf     = (ushort_t*)w; w += (size_t)NN * 128 * 2;
    S.hAbf       = (ushort_t*)w; w += (size_t)NN * 64 * 2;
    S.hBbf       = (ushort_t*)w; w += (size_t)NN * 128 * 2;
    S.wt1        = (ushort_t*)w; w += 128 * 64 * 2;
    S.wt2        = (ushort_t*)w; w += 64 * 128 * 2;
    S.wt3        = (ushort_t*)w; w += 128 * 64 * 2;
    S.el         = (float*)w;    w += (size_t)NN * 4;
    S.er         = (float*)w;    w += (size_t)NN * 4;
    S.s1         = (float*)w;    w += (size_t)NN * 4;
    S.s2         = (float*)w;    w += (size_t)NN * 4;
    S.off        = (int*)w;      w += (size_t)(NN + 1) * 4;
    S.csrsrc     = (int*)w;      w += (size_t)NE * 4;
    S.gh         = (uint_t*)w;   w += (size_t)NT * NBKT * 4;
    S.bucketbase = (uint_t*)w;   w += (size_t)(NBKT + 1) * 4;
    S.pairbuf    = (int2*)w;     w += (size_t)NE * 8;

    // prep: bf16 conversions (independent of CSR build; stream-serial)
    conv_x<<<(NN * 128 / 8 + 255) / 256, 256, 0, stream>>>(x, S.xbf, NN * 128 / 8);
    prep_w<<<1, 256, 0, stream>>>(W1, W2, W3, S.wt1, S.wt2, S.wt3);

    // build dst-CSR once (bucketed counting sort); reused by all 3 layers
    part_hist<<<NT, 256, 0, stream>>>(dst, S.gh);
    scan_gh<<<1, 256, 0, stream>>>(S.gh, S.bucketbase);
    part_scatter<<<NT, 256, 0, stream>>>(src, dst, S.gh, S.pairbuf);
    bucket_csr<<<NBKT, 256, 0, stream>>>(S.pairbuf, S.bucketbase, S.off, S.csrsrc);

    float* out_h   = (float*)d_out;
    float* out_pos = out_h + (size_t)NN * 64;
    float* out_neg = out_pos + NE;

    const int NBLK = NN / 16;          // 3125
    const int AGG_GRID = (NN * 32 + 255) / 256;

    // layer 1: xbf @ W1 -> featbf[N,64] + el/er; agg -> hAbf (bf16, relu)
    gemm_mfma<128, 64><<<NBLK, 256, 0, stream>>>(S.xbf, S.wt1, al1, ar1, S.featbf, S.el, S.er, NN);
    gat_agg2<64, false, true><<<AGG_GRID, 256, 0, stream>>>(
        S.off, S.csrsrc, S.el, S.er, S.featbf, b1, S.hAbf, nullptr, S.s1, S.s2, NN, 1);

    // layer 2: hAbf @ W2 -> featbf[N,128] + el/er; agg -> hBbf (bf16, relu)
    gemm_mfma<64, 128><<<NBLK, 256, 0, stream>>>(S.hAbf, S.wt2, al2, ar2, S.featbf, S.el, S.er, NN);
    gat_agg2<128, false, true><<<AGG_GRID, 256, 0, stream>>>(
        S.off, S.csrsrc, S.el, S.er, S.featbf, b2, S.hBbf, nullptr, S.s1, S.s2, NN, 1);

    // layer 3: hBbf @ W3 -> featbf[N,64] + el/er; agg -> fp32 h to d_out + link-pred partials
    gemm_mfma<128, 64><<<NBLK, 256, 0, stream>>>(S.hBbf, S.wt3, al3, ar3, S.featbf, S.el, S.er, NN);
    gat_agg2<64, true, false><<<AGG_GRID, 256, 0, stream>>>(
        S.off, S.csrsrc, S.el, S.er, S.featbf, b3, out_h, lpW, S.s1, S.s2, NN, 0);

    scores2_k<<<(2 * NE + 255) / 256, 256, 0, stream>>>(src, dst, nsrc, ndst,
                                                        S.s1, S.s2, lpb, out_pos, out_neg, NE);
}